// Round 3
// baseline (283.757 us; speedup 1.0000x reference)
//
#include <hip/hip_runtime.h>

// Problem constants
#define B_  8192
#define L_  10
#define D_  128
#define H_  64
#define OUT_ 5

typedef _Float16 h2 __attribute__((ext_vector_type(2)));
typedef _Float16 f16x8 __attribute__((ext_vector_type(8)));
typedef float f32x4 __attribute__((ext_vector_type(4)));
typedef unsigned int uint;

// ws dword layout:
#define WS_ENCPK   0        // [kp<96][l]: uint4, dword q = half2(W[q*64+l][2kp], [2kp+1]); k<128: Wih, else Whh
#define WS_ENCB    24576    // 256 floats: [l][q] = bih+bhh
#define WS_DECY2   24832    // [i<4][l<64]: uint4, comp q = half2(decWih[q*64+l][2i], [2i+1]) zero-padded k>=5
#define WS_DECPK   26112    // [ep<32][l]: uint4, half2(decWhh[q*64+l][2ep], [2ep+1])
#define WS_DECB    34304    // 256 floats: [u][q]
#define WS_W1HCP   34560    // [ep<32][l]: uint2 {half2 W1h pair, half2 W1c pair}
#define WS_W1XP    38656    // [ep<32][l]: uint half2 W1x pair
#define WS_G       40960    // G'[row=(b*L+t)][j 0..255] f16, bias folded (512B/row)

__device__ __forceinline__ float sigmf(float x){ return 1.f/(1.f+__expf(-x)); }
__device__ __forceinline__ float tanhf_(float x){ return 1.f - 2.f/(1.f+__expf(2.f*x)); }
__device__ __forceinline__ uint pack_rtz(float a, float b){
  return __builtin_bit_cast(uint, __builtin_amdgcn_cvt_pkrtz(a, b));
}
__device__ __forceinline__ uint pack_rtn(float a, float b){
  h2 v; v.x = (_Float16)a; v.y = (_Float16)b;
  return __builtin_bit_cast(uint, v);
}
__device__ __forceinline__ float2 unpk(uint u){
  h2 v = __builtin_bit_cast(h2, u);
  return make_float2((float)v.x, (float)v.y);
}

union U4 { uint u[4]; uint4 q; f16x8 v; };

__global__ void prep_kernel(const float* __restrict__ encWih, const float* __restrict__ encWhh,
                            const float* __restrict__ encbih, const float* __restrict__ encbhh,
                            const float* __restrict__ decWih, const float* __restrict__ decWhh,
                            const float* __restrict__ decbih, const float* __restrict__ decbhh,
                            const float* __restrict__ w1, float* __restrict__ wsf)
{
  uint* ws = (uint*)wsf;
  int stride = gridDim.x * blockDim.x;
  int tid0 = blockIdx.x * blockDim.x + threadIdx.x;

  for (int idx = tid0; idx < 96*64; idx += stride) {
    int kp = idx >> 6, l = idx & 63;
    uint4 o; uint* op = (uint*)&o;
    #pragma unroll
    for (int q=0;q<4;++q){
      int j = q*64 + l;
      int k0 = 2*kp, k1 = 2*kp+1;
      float a = (k0 < 128) ? encWih[j*128 + k0] : encWhh[j*64 + (k0-128)];
      float b = (k1 < 128) ? encWih[j*128 + k1] : encWhh[j*64 + (k1-128)];
      op[q] = pack_rtn(a,b);
    }
    ((uint4*)(ws + WS_ENCPK))[idx] = o;
  }
  for (int idx = tid0; idx < 256; idx += stride) {
    int l = idx >> 2, q = idx & 3, j = q*64+l;
    wsf[WS_ENCB+idx] = encbih[j] + encbhh[j];
  }
  // dec Wih packed for MFMA kf0 (k = 0..4, zero-padded to 8)
  for (int idx = tid0; idx < 4*64; idx += stride) {
    int i = idx >> 6, l = idx & 63;
    uint4 o; uint* op = (uint*)&o;
    #pragma unroll
    for (int q=0;q<4;++q){
      int j = q*64 + l;
      int k0 = 2*i, k1 = 2*i+1;
      float a = (k0 < 5) ? decWih[j*5 + k0] : 0.f;
      float b = (k1 < 5) ? decWih[j*5 + k1] : 0.f;
      op[q] = pack_rtn(a,b);
    }
    ((uint4*)(ws + WS_DECY2))[idx] = o;
  }
  for (int idx = tid0; idx < 32*64; idx += stride) {
    int ep = idx >> 6, l = idx & 63;
    uint4 o; uint* op = (uint*)&o;
    #pragma unroll
    for (int q=0;q<4;++q){
      int j = q*64 + l;
      op[q] = pack_rtn(decWhh[j*64 + 2*ep], decWhh[j*64 + 2*ep+1]);
    }
    ((uint4*)(ws + WS_DECPK))[idx] = o;
  }
  for (int idx = tid0; idx < 256; idx += stride) {
    int l = idx >> 2, q = idx & 3, j = q*64+l;
    wsf[WS_DECB+idx] = decbih[j] + decbhh[j];
  }
  for (int idx = tid0; idx < 32*64; idx += stride) {
    int ep = idx >> 6, l = idx & 63;
    uint2 o;
    o.x = pack_rtn(w1[l*192 + 2*ep],      w1[l*192 + 2*ep+1]);
    o.y = pack_rtn(w1[l*192 + 64 + 2*ep], w1[l*192 + 64 + 2*ep+1]);
    ((uint2*)(ws + WS_W1HCP))[idx] = o;
  }
  for (int idx = tid0; idx < 32*64; idx += stride) {
    int ep = idx >> 6, l = idx & 63;
    ws[WS_W1XP + idx] = pack_rtn(w1[l*192 + 128 + 2*ep], w1[l*192 + 128 + 2*ep+1]);
  }
}

// MFMA G-producer (unchanged — verified): G'[(b,t)][j] f16, bias folded.
__global__ __launch_bounds__(256, 2) void gemmG_mfma(
    const float* __restrict__ x, const float* __restrict__ enc_attn_w,
    const float* __restrict__ ws, _Float16* __restrict__ Gh)
{
  const int l   = threadIdx.x & 63;
  const int w   = threadIdx.x >> 6;
  const int col = l & 15;
  const int g   = l >> 4;
  const int b0  = blockIdx.x * 16;
  const uint* wsu = (const uint*)ws;

  f16x8 afr[4][4];
  #pragma unroll
  for (int im=0; im<4; ++im){
    #pragma unroll
    for (int kf=0; kf<4; ++kf){
      U4 cv;
      #pragma unroll
      for (int i=0;i<4;++i){
        int kp = kf*16 + g*4 + i;
        int lsrc = im*16 + col;
        cv.u[i] = wsu[WS_ENCPK + (kp*64 + lsrc)*4 + w];
      }
      afr[im][kf] = cv.v;
    }
  }
  float bias[4][4];
  #pragma unroll
  for (int im=0; im<4; ++im)
    #pragma unroll
    for (int r=0; r<4; ++r)
      bias[im][r] = ws[WS_ENCB + (im*16 + g*4 + r)*4 + w];

  float wxv[L_];
  #pragma unroll
  for (int t=0;t<L_;++t) wxv[t] = enc_attn_w[2*H_ + t];

  const float* xb = x + (size_t)(b0+col)*(L_*D_);

  float sc[4][8];
  #pragma unroll
  for (int kf=0;kf<4;++kf)
    #pragma unroll
    for (int hh=0;hh<8;++hh) sc[kf][hh]=0.f;
  #pragma unroll 2
  for (int t=0;t<L_;++t){
    float wx = wxv[t];
    #pragma unroll
    for (int kf=0;kf<4;++kf){
      const float* p = xb + t*D_ + kf*32 + g*8;
      float4 x0 = *(const float4*)p, x1 = *(const float4*)(p+4);
      sc[kf][0]+=x0.x*wx; sc[kf][1]+=x0.y*wx; sc[kf][2]+=x0.z*wx; sc[kf][3]+=x0.w*wx;
      sc[kf][4]+=x1.x*wx; sc[kf][5]+=x1.y*wx; sc[kf][6]+=x1.z*wx; sc[kf][7]+=x1.w*wx;
    }
  }
  float m = sc[0][0];
  #pragma unroll
  for (int kf=0;kf<4;++kf)
    #pragma unroll
    for (int hh=0;hh<8;++hh) m = fmaxf(m, sc[kf][hh]);
  m = fmaxf(m, __shfl_xor(m,16));
  m = fmaxf(m, __shfl_xor(m,32));
  float ss = 0.f;
  #pragma unroll
  for (int kf=0;kf<4;++kf)
    #pragma unroll
    for (int hh=0;hh<8;++hh){ sc[kf][hh] = __expf(sc[kf][hh]-m); ss += sc[kf][hh]; }
  ss += __shfl_xor(ss,16);
  ss += __shfl_xor(ss,32);
  float inv = 1.f/ss;
  #pragma unroll
  for (int kf=0;kf<4;++kf)
    #pragma unroll
    for (int hh=0;hh<8;++hh) sc[kf][hh] *= inv;

  #pragma unroll 2
  for (int t=0;t<L_;++t){
    f16x8 bfr[4];
    #pragma unroll
    for (int kf=0;kf<4;++kf){
      const float* p = xb + t*D_ + kf*32 + g*8;
      float4 x0 = *(const float4*)p, x1 = *(const float4*)(p+4);
      U4 cv;
      cv.u[0] = pack_rtz(sc[kf][0]*x0.x, sc[kf][1]*x0.y);
      cv.u[1] = pack_rtz(sc[kf][2]*x0.z, sc[kf][3]*x0.w);
      cv.u[2] = pack_rtz(sc[kf][4]*x1.x, sc[kf][5]*x1.y);
      cv.u[3] = pack_rtz(sc[kf][6]*x1.z, sc[kf][7]*x1.w);
      bfr[kf] = cv.v;
    }
    _Float16* grow = Gh + ((size_t)(b0+col)*L_ + t)*256;
    #pragma unroll
    for (int im=0;im<4;++im){
      f32x4 acc = { bias[im][0], bias[im][1], bias[im][2], bias[im][3] };
      #pragma unroll
      for (int kf=0;kf<4;++kf)
        acc = __builtin_amdgcn_mfma_f32_16x16x32_f16(afr[im][kf], bfr[kf], acc, 0, 0, 0);
      uint2 o = make_uint2(pack_rtn(acc[0],acc[1]), pack_rtn(acc[2],acc[3]));
      *(uint2*)(grow + (4*w+im)*16 + g*4) = o;
    }
  }
}

// LDS arena offsets (bytes)
#define SM_HXE   0        // uint [2][16][36]            = 4608   (enc only)
#define SM_XES   4608     // f16  [10][16][72]           = 23040  (enc..preC)
#define SM_TMPF  0        // float[10][16][5][4]         = 12800  (fxe phase; aliases HXE/XES)
#define SM_TMPG  12800    // float[10][16][5][4]         = 12800
#define SM_HXD   27648    // uint [2][16][36]            = 4608
#define SM_CXD   32256    // uint [2][16][36]            = 4608
#define SM_SRED  36864    // float[10][16][4]            = 2560
#define SM_FXE   39424    // float[16][10][5]            = 3200
#define SM_GXE   42624    // float[16][10][5]            = 3200
#define SM_YBS   45824    // float[16][50]               = 3200
#define SM_TOTAL 49024

// Cooperative darnn: block = 4 waves, 16 batch rows. Wave w owns u-slice [16w,16w+16).
// vs R2: G double-prefetch; y_hist LDS-staged; fxe/gxe precompute kills per-t ctx,
// the yred reduction and 1 barrier/t (dec 3->2 barriers).
__global__ __launch_bounds__(256, 2) void darnn_kernel(
    const float* __restrict__ y_hist,
    const float* __restrict__ h0e, const float* __restrict__ c0e,
    const float* __restrict__ h0d, const float* __restrict__ c0d,
    const float* __restrict__ dec_attn_b1, const float* __restrict__ dec_attn_w2,
    const float* __restrict__ fc_w, const float* __restrict__ fc_b,
    const float* __restrict__ fcout_w, const float* __restrict__ fcout_b,
    const float* __restrict__ ws, const uint2* __restrict__ Gp,
    float* __restrict__ out)
{
  const int tid = threadIdx.x;
  const int l   = tid & 63;
  const int w   = tid >> 6;
  const int col = l & 15;          // batch sub-row
  const int g   = l >> 4;          // k-group
  const int b0  = blockIdx.x * 16;
  const int lw  = 16*w + col;      // row into 64-wide weight tables
  const int u0  = 16*w + 4*g;      // first hidden-unit of this lane's C-slice

  const uint* wsu = (const uint*)ws;
  const _Float16* Gh = (const _Float16*)Gp;

  __shared__ __align__(16) char smem_[SM_TOTAL];
  uint     (*hxE)[16][36] = reinterpret_cast<uint(*)[16][36]>(smem_ + SM_HXE);
  _Float16 (*xeS)[16][72] = reinterpret_cast<_Float16(*)[16][72]>(smem_ + SM_XES);
  float* tmpF = (float*)(smem_ + SM_TMPF);
  float* tmpG = (float*)(smem_ + SM_TMPG);
  uint     (*hxD)[16][36] = reinterpret_cast<uint(*)[16][36]>(smem_ + SM_HXD);
  uint     (*cxD)[16][36] = reinterpret_cast<uint(*)[16][36]>(smem_ + SM_CXD);
  float* sred = (float*)(smem_ + SM_SRED);
  float* fxeS = (float*)(smem_ + SM_FXE);
  float* gxeS = (float*)(smem_ + SM_GXE);
  float* ybS  = (float*)(smem_ + SM_YBS);

  // ---- early global loads (latency hidden under encoder) ----
  const bool yact = (tid < 200);
  if (yact){
    float4 yreg = *(const float4*)(y_hist + (size_t)b0*50 + tid*4);
    *(float4*)(ybS + tid*4) = yreg;
  }
  float4 hd4 = *(const float4*)(h0d + (size_t)(b0+col)*64 + u0);
  float4 cd4 = *(const float4*)(c0d + (size_t)(b0+col)*64 + u0);

  // ---------------- hoisted enc weight fragments ----------------
  f16x8 aE[4][2];
  #pragma unroll
  for (int q=0;q<4;++q)
    #pragma unroll
    for (int kf=0;kf<2;++kf){
      U4 cv;
      #pragma unroll
      for (int i=0;i<4;++i)
        cv.u[i] = wsu[WS_ENCPK + ((64 + kf*16 + g*4 + i)*64 + lw)*4 + q];
      aE[q][kf] = cv.v;
    }

  // ---------------- encoder ----------------
  float h[4], c[4], xer[L_][4];
  {
    float4 hv = *(const float4*)(h0e + (size_t)(b0+col)*64 + u0);
    float4 cv = *(const float4*)(c0e + (size_t)(b0+col)*64 + u0);
    h[0]=hv.x; h[1]=hv.y; h[2]=hv.z; h[3]=hv.w;
    c[0]=cv.x; c[1]=cv.y; c[2]=cv.z; c[3]=cv.w;
  }
  *(uint2*)&hxE[0][col][u0>>1] = make_uint2(pack_rtz(h[0],h[1]), pack_rtz(h[2],h[3]));
  __syncthreads();

  // G double-prefetch
  uint2 gq[2][4];
  {
    const _Float16* g0 = Gh + ((size_t)(b0+col)*L_ + 0)*256;
    const _Float16* g1 = Gh + ((size_t)(b0+col)*L_ + 1)*256;
    #pragma unroll
    for (int q=0;q<4;++q){
      gq[0][q] = *(const uint2*)(g0 + q*64 + u0);
      gq[1][q] = *(const uint2*)(g1 + q*64 + u0);
    }
  }

  int p = 0;
  for (int t=0; t<L_; ++t){
    const int cb = t&1;
    f32x4 acc[4];
    #pragma unroll
    for (int q=0;q<4;++q){
      float2 u0f = unpk(gq[cb][q].x), u1f = unpk(gq[cb][q].y);
      acc[q][0]=u0f.x; acc[q][1]=u0f.y; acc[q][2]=u1f.x; acc[q][3]=u1f.y;
    }
    if (t+2<L_){
      const _Float16* gn = Gh + ((size_t)(b0+col)*L_ + (t+2))*256;
      #pragma unroll
      for (int q=0;q<4;++q) gq[cb][q] = *(const uint2*)(gn + q*64 + u0);
    }
    f16x8 hB[2];
    { U4 t0; t0.q = *(const uint4*)&hxE[p][col][g*4];      hB[0]=t0.v; }
    { U4 t1; t1.q = *(const uint4*)&hxE[p][col][16 + g*4]; hB[1]=t1.v; }

    #pragma unroll
    for (int q=0;q<4;++q){
      acc[q] = __builtin_amdgcn_mfma_f32_16x16x32_f16(aE[q][0], hB[0], acc[q], 0,0,0);
      acc[q] = __builtin_amdgcn_mfma_f32_16x16x32_f16(aE[q][1], hB[1], acc[q], 0,0,0);
    }
    #pragma unroll
    for (int r=0;r<4;++r){
      float ig=sigmf(acc[0][r]), fg=sigmf(acc[1][r]), gg=tanhf_(acc[2][r]), og=sigmf(acc[3][r]);
      c[r]=fg*c[r]+ig*gg;
      h[r]=og*tanhf_(c[r]);
      xer[t][r]=h[r];
    }
    uint2 hpk = make_uint2(pack_rtz(h[0],h[1]), pack_rtz(h[2],h[3]));
    *(uint2*)&xeS[t][col][u0] = hpk;
    *(uint2*)&hxE[p^1][col][u0>>1] = hpk;
    __syncthreads();
    p ^= 1;
  }

  // ---------------- pre[l, lt, b] = xe @ W1x^T ----------------
  f16x8 aX[2];
  #pragma unroll
  for (int kf=0;kf<2;++kf){
    U4 cv;
    #pragma unroll
    for (int i=0;i<4;++i) cv.u[i] = wsu[WS_W1XP + (kf*16 + g*4 + i)*64 + lw];
    aX[kf] = cv.v;
  }
  f32x4 preC[L_];
  #pragma unroll
  for (int lt=0;lt<L_;++lt){
    f32x4 a = {0.f,0.f,0.f,0.f};
    U4 bu0, bu1;
    bu0.q = *(const uint4*)&xeS[lt][col][g*8];
    bu1.q = *(const uint4*)&xeS[lt][col][32 + g*8];
    a = __builtin_amdgcn_mfma_f32_16x16x32_f16(aX[0], bu0.v, a, 0,0,0);
    a = __builtin_amdgcn_mfma_f32_16x16x32_f16(aX[1], bu1.v, a, 0,0,0);
    preC[lt] = a;
  }
  __syncthreads();   // xeS reads complete before temp overwrite

  // ---------------- fxe/gxe precompute (f32-exact from xer) ----------------
  {
    float fw1v[OUT_][4], gw1v[OUT_][4];
    #pragma unroll
    for (int o2=0;o2<OUT_;++o2)
      #pragma unroll
      for (int r=0;r<4;++r){
        fw1v[o2][r] = fc_w[o2*69 + u0 + r];
        gw1v[o2][r] = fcout_w[o2*128 + 64 + u0 + r];
      }
    #pragma unroll
    for (int lt=0;lt<L_;++lt){
      #pragma unroll
      for (int o2=0;o2<OUT_;++o2){
        float pf = fw1v[o2][0]*xer[lt][0] + fw1v[o2][1]*xer[lt][1]
                 + fw1v[o2][2]*xer[lt][2] + fw1v[o2][3]*xer[lt][3];
        float pg = gw1v[o2][0]*xer[lt][0] + gw1v[o2][1]*xer[lt][1]
                 + gw1v[o2][2]*xer[lt][2] + gw1v[o2][3]*xer[lt][3];
        pf += __shfl_xor(pf,16); pf += __shfl_xor(pf,32);
        pg += __shfl_xor(pg,16); pg += __shfl_xor(pg,32);
        if (g==0){
          tmpF[((lt*16+col)*OUT_+o2)*4 + w] = pf;
          tmpG[((lt*16+col)*OUT_+o2)*4 + w] = pg;
        }
      }
    }
  }
  __syncthreads();
  for (int idx=tid; idx<800; idx+=256){
    float4 f4 = *(const float4*)(tmpF + idx*4);
    float4 g4 = *(const float4*)(tmpG + idx*4);
    int o2 = idx % 5, rest = idx / 5;
    int b  = rest % 16, lt = rest / 16;
    fxeS[b*50 + lt*5 + o2] = f4.x+f4.y+f4.z+f4.w;
    gxeS[b*50 + lt*5 + o2] = g4.x+g4.y+g4.z+g4.w;
  }

  // ---------------- decoder hoists ----------------
  f16x8 aW1[4];   // K=128: kf0,1 = W1h; kf2,3 = W1c
  #pragma unroll
  for (int kf=0;kf<4;++kf){
    U4 cv;
    #pragma unroll
    for (int i=0;i<4;++i){
      int ep = (kf&1)*16 + g*4 + i;
      cv.u[i] = wsu[WS_W1HCP + (ep*64 + lw)*2 + (kf>>1)];
    }
    aW1[kf] = cv.v;
  }
  f16x8 aGh[4][2];
  #pragma unroll
  for (int q=0;q<4;++q)
    #pragma unroll
    for (int kf=0;kf<2;++kf){
      U4 cv;
      #pragma unroll
      for (int i=0;i<4;++i)
        cv.u[i] = wsu[WS_DECPK + ((kf*16 + g*4 + i)*64 + lw)*4 + q];
      aGh[q][kf] = cv.v;
    }
  f16x8 aG0[4];
  #pragma unroll
  for (int q=0;q<4;++q){
    U4 cv;
    #pragma unroll
    for (int i=0;i<4;++i)
      cv.u[i] = (g==0) ? wsu[WS_DECY2 + (i*64 + lw)*4 + q] : 0u;
    aG0[q] = cv.v;
  }
  float4 bD[4];
  #pragma unroll
  for (int r=0;r<4;++r) bD[r] = *(const float4*)(ws + WS_DECB + (u0+r)*4);
  float4 b1v = *(const float4*)(dec_attn_b1 + u0);
  float4 w2v = *(const float4*)(dec_attn_w2 + u0);
  float fcbv[OUT_], fw2v[OUT_][OUT_];
  #pragma unroll
  for (int o2=0;o2<OUT_;++o2){
    fcbv[o2] = fc_b[o2];
    #pragma unroll
    for (int j=0;j<OUT_;++j) fw2v[o2][j] = fc_w[o2*69 + 64 + j];
  }

  // ---------------- decoder init ----------------
  h[0]=hd4.x; h[1]=hd4.y; h[2]=hd4.z; h[3]=hd4.w;
  c[0]=cd4.x; c[1]=cd4.y; c[2]=cd4.z; c[3]=cd4.w;
  *(uint2*)&hxD[0][col][u0>>1] = make_uint2(pack_rtz(h[0],h[1]), pack_rtz(h[2],h[3]));
  *(uint2*)&cxD[0][col][u0>>1] = make_uint2(pack_rtz(c[0],c[1]), pack_rtz(c[2],c[3]));
  __syncthreads();

  float at[L_];
  float inv = 0.f;
  p = 0;
  for (int t=0; t<L_; ++t){
    f16x8 hB[2], cB[2];
    { U4 t0; t0.q = *(const uint4*)&hxD[p][col][g*4];      hB[0]=t0.v; }
    { U4 t1; t1.q = *(const uint4*)&hxD[p][col][16 + g*4]; hB[1]=t1.v; }
    { U4 t2; t2.q = *(const uint4*)&cxD[p][col][g*4];      cB[0]=t2.v; }
    { U4 t3; t3.q = *(const uint4*)&cxD[p][col][16 + g*4]; cB[1]=t3.v; }

    // vb = b1 + h@W1h^T + c@W1c^T
    f32x4 vb = { b1v.x, b1v.y, b1v.z, b1v.w };
    vb = __builtin_amdgcn_mfma_f32_16x16x32_f16(aW1[0], hB[0], vb, 0,0,0);
    vb = __builtin_amdgcn_mfma_f32_16x16x32_f16(aW1[1], hB[1], vb, 0,0,0);
    vb = __builtin_amdgcn_mfma_f32_16x16x32_f16(aW1[2], cB[0], vb, 0,0,0);
    vb = __builtin_amdgcn_mfma_f32_16x16x32_f16(aW1[3], cB[1], vb, 0,0,0);

    // scores: wave-partial over this wave's 16 l's
    #pragma unroll
    for (int lt=0;lt<L_;++lt){
      float zp = tanhf_(preC[lt][0] + vb[0]) * w2v.x
               + tanhf_(preC[lt][1] + vb[1]) * w2v.y
               + tanhf_(preC[lt][2] + vb[2]) * w2v.z
               + tanhf_(preC[lt][3] + vb[3]) * w2v.w;
      zp += __shfl_xor(zp,16);
      zp += __shfl_xor(zp,32);
      at[lt] = zp;
    }
    if (g==0){
      #pragma unroll
      for (int lt=0;lt<L_;++lt) sred[(lt*16+col)*4 + w] = at[lt];
    }
    __syncthreads();
    #pragma unroll
    for (int lt=0;lt<L_;++lt){
      float4 s4 = *(const float4*)(sred + (lt*16+col)*4);
      at[lt] = s4.x + s4.y + s4.z + s4.w;
    }
    // softmax over L (unnormalized exp in at[], inv kept)
    float mx = at[0];
    #pragma unroll
    for (int lt=1;lt<L_;++lt) mx = fmaxf(mx, at[lt]);
    float ssum = 0.f;
    #pragma unroll
    for (int lt=0;lt<L_;++lt){ at[lt] = __expf(at[lt]-mx); ssum += at[lt]; }
    inv = 1.f/ssum;

    // y_tilde on g==0 lanes via fxe (ctx never materialized)
    U4 ycv; ycv.u[0]=0u; ycv.u[1]=0u; ycv.u[2]=0u; ycv.u[3]=0u;
    if (g==0){
      const float* fx = fxeS + col*50;
      const float* yb = ybS + col*50 + t*5;
      float yt[OUT_];
      #pragma unroll
      for (int o2=0;o2<OUT_;++o2){
        float s = 0.f;
        #pragma unroll
        for (int lt=0;lt<L_;++lt) s += at[lt]*fx[lt*5+o2];
        float v = s*inv + fcbv[o2];
        #pragma unroll
        for (int j=0;j<OUT_;++j) v += yb[j]*fw2v[o2][j];
        yt[o2] = v;
      }
      ycv.u[0] = pack_rtn(yt[0], yt[1]);
      ycv.u[1] = pack_rtn(yt[2], yt[3]);
      ycv.u[2] = pack_rtn(yt[4], 0.f);
    }
    // gates = bias + y_tilde@Wih^T + h@Whh^T
    f32x4 accQ[4];
    #pragma unroll
    for (int q=0;q<4;++q){
      accQ[q][0]=((const float*)&bD[0])[q];
      accQ[q][1]=((const float*)&bD[1])[q];
      accQ[q][2]=((const float*)&bD[2])[q];
      accQ[q][3]=((const float*)&bD[3])[q];
    }
    #pragma unroll
    for (int q=0;q<4;++q){
      accQ[q] = __builtin_amdgcn_mfma_f32_16x16x32_f16(aG0[q], ycv.v, accQ[q], 0,0,0);
      accQ[q] = __builtin_amdgcn_mfma_f32_16x16x32_f16(aGh[q][0], hB[0], accQ[q], 0,0,0);
      accQ[q] = __builtin_amdgcn_mfma_f32_16x16x32_f16(aGh[q][1], hB[1], accQ[q], 0,0,0);
    }
    #pragma unroll
    for (int r=0;r<4;++r){
      float ig=sigmf(accQ[0][r]), fg=sigmf(accQ[1][r]), gg=tanhf_(accQ[2][r]), og=sigmf(accQ[3][r]);
      c[r]=fg*c[r]+ig*gg;
      h[r]=og*tanhf_(c[r]);
    }
    *(uint2*)&hxD[p^1][col][u0>>1] = make_uint2(pack_rtz(h[0],h[1]), pack_rtz(h[2],h[3]));
    *(uint2*)&cxD[p^1][col][u0>>1] = make_uint2(pack_rtz(c[0],c[1]), pack_rtz(c[2],c[3]));
    __syncthreads();
    p ^= 1;
  }

  // ---------------- epilogue: out = concat(h, ctx) @ fcout^T + b ----------------
  {
    float fcA[OUT_][4];
    #pragma unroll
    for (int o2=0;o2<OUT_;++o2)
      #pragma unroll
      for (int r=0;r<4;++r) fcA[o2][r] = fcout_w[o2*128 + u0 + r];
    #pragma unroll
    for (int o2=0;o2<OUT_;++o2){
      float pv = fcA[o2][0]*h[0] + fcA[o2][1]*h[1] + fcA[o2][2]*h[2] + fcA[o2][3]*h[3];
      pv += __shfl_xor(pv,16);
      pv += __shfl_xor(pv,32);
      if (g==0) sred[(o2*16+col)*4 + w] = pv;
    }
  }
  __syncthreads();
  if (w==0 && g==0){
    const float* gx = gxeS + col*50;
    #pragma unroll
    for (int o2=0;o2<OUT_;++o2){
      float4 s4 = *(const float4*)(sred + (o2*16+col)*4);
      float s = 0.f;
      #pragma unroll
      for (int lt=0;lt<L_;++lt) s += at[lt]*gx[lt*5+o2];
      out[(size_t)(b0+col)*OUT_ + o2] = s4.x+s4.y+s4.z+s4.w + s*inv + fcout_b[o2];
    }
  }
}

extern "C" void kernel_launch(void* const* d_in, const int* in_sizes, int n_in,
                              void* d_out, int out_size, void* d_ws, size_t ws_size,
                              hipStream_t stream) {
  const float* x          = (const float*)d_in[0];
  const float* y_hist     = (const float*)d_in[1];
  const float* h0_enc     = (const float*)d_in[2];
  const float* c0_enc     = (const float*)d_in[3];
  const float* h0_dec     = (const float*)d_in[4];
  const float* c0_dec     = (const float*)d_in[5];
  const float* enc_attn_w = (const float*)d_in[6];
  const float* enc_Wih    = (const float*)d_in[8];
  const float* enc_Whh    = (const float*)d_in[9];
  const float* enc_bih    = (const float*)d_in[10];
  const float* enc_bhh    = (const float*)d_in[11];
  const float* dec_attn_w1= (const float*)d_in[12];
  const float* dec_attn_b1= (const float*)d_in[13];
  const float* dec_attn_w2= (const float*)d_in[14];
  const float* dec_Wih    = (const float*)d_in[16];
  const float* dec_Whh    = (const float*)d_in[17];
  const float* dec_bih    = (const float*)d_in[18];
  const float* dec_bhh    = (const float*)d_in[19];
  const float* fc_w       = (const float*)d_in[20];
  const float* fc_b       = (const float*)d_in[21];
  const float* fcout_w    = (const float*)d_in[22];
  const float* fcout_b    = (const float*)d_in[23];
  float* ws = (float*)d_ws;
  float* out = (float*)d_out;
  uint2* Gp = (uint2*)((uint*)d_ws + WS_G);

  hipLaunchKernelGGL(prep_kernel, dim3(128), dim3(256), 0, stream,
                     enc_Wih, enc_Whh, enc_bih, enc_bhh,
                     dec_Wih, dec_Whh, dec_bih, dec_bhh,
                     dec_attn_w1, ws);
  hipLaunchKernelGGL(gemmG_mfma, dim3(B_/16), dim3(256), 0, stream,
                     x, enc_attn_w, ws, (_Float16*)Gp);
  hipLaunchKernelGGL(darnn_kernel, dim3(B_/16), dim3(256), 0, stream,
                     y_hist, h0_enc, c0_enc, h0_dec, c0_dec,
                     dec_attn_b1, dec_attn_w2,
                     fc_w, fc_b, fcout_w, fcout_b, ws, Gp, out);
}

// Round 4
// 253.890 us; speedup vs baseline: 1.1176x; 1.1176x over previous
//
#include <hip/hip_runtime.h>

// Problem constants
#define B_  8192
#define L_  10
#define D_  128
#define H_  64
#define OUT_ 5

typedef _Float16 h2 __attribute__((ext_vector_type(2)));
typedef _Float16 f16x8 __attribute__((ext_vector_type(8)));
typedef float f32x4 __attribute__((ext_vector_type(4)));
typedef unsigned int uint;

// ws dword layout:
#define WS_ENCPK   0        // [kp<96][l]: uint4, dword q = half2(W[q*64+l][2kp], [2kp+1]); k<128: Wih, else Whh
#define WS_ENCB    24576    // 256 floats: [l][q] = bih+bhh
#define WS_DECY2   24832    // [i<4][l<64]: uint4, comp q = half2(decWih[q*64+l][2i], [2i+1]) zero-padded k>=5
#define WS_DECPK   26112    // [ep<32][l]: uint4, half2(decWhh[q*64+l][2ep], [2ep+1])
#define WS_DECB    34304    // 256 floats: [u][q]
#define WS_W1HCP   34560    // [ep<32][l]: uint2 {half2 W1h pair, half2 W1c pair}
#define WS_W1XP    38656    // [ep<32][l]: uint half2 W1x pair
#define WS_G       40960    // G'[row=(b*L+t)][j 0..255] f16, bias folded (512B/row)

__device__ __forceinline__ float sigmf(float x){ return 1.f/(1.f+__expf(-x)); }
__device__ __forceinline__ float tanhf_(float x){ return 1.f - 2.f/(1.f+__expf(2.f*x)); }
__device__ __forceinline__ uint pack_rtz(float a, float b){
  return __builtin_bit_cast(uint, __builtin_amdgcn_cvt_pkrtz(a, b));
}
__device__ __forceinline__ uint pack_rtn(float a, float b){
  h2 v; v.x = (_Float16)a; v.y = (_Float16)b;
  return __builtin_bit_cast(uint, v);
}
__device__ __forceinline__ float2 unpk(uint u){
  h2 v = __builtin_bit_cast(h2, u);
  return make_float2((float)v.x, (float)v.y);
}

union U4 { uint u[4]; uint4 q; f16x8 v; };

__global__ void prep_kernel(const float* __restrict__ encWih, const float* __restrict__ encWhh,
                            const float* __restrict__ encbih, const float* __restrict__ encbhh,
                            const float* __restrict__ decWih, const float* __restrict__ decWhh,
                            const float* __restrict__ decbih, const float* __restrict__ decbhh,
                            const float* __restrict__ w1, float* __restrict__ wsf)
{
  uint* ws = (uint*)wsf;
  int stride = gridDim.x * blockDim.x;
  int tid0 = blockIdx.x * blockDim.x + threadIdx.x;

  for (int idx = tid0; idx < 96*64; idx += stride) {
    int kp = idx >> 6, l = idx & 63;
    uint4 o; uint* op = (uint*)&o;
    #pragma unroll
    for (int q=0;q<4;++q){
      int j = q*64 + l;
      int k0 = 2*kp, k1 = 2*kp+1;
      float a = (k0 < 128) ? encWih[j*128 + k0] : encWhh[j*64 + (k0-128)];
      float b = (k1 < 128) ? encWih[j*128 + k1] : encWhh[j*64 + (k1-128)];
      op[q] = pack_rtn(a,b);
    }
    ((uint4*)(ws + WS_ENCPK))[idx] = o;
  }
  for (int idx = tid0; idx < 256; idx += stride) {
    int l = idx >> 2, q = idx & 3, j = q*64+l;
    wsf[WS_ENCB+idx] = encbih[j] + encbhh[j];
  }
  // dec Wih packed for MFMA kf0 (k = 0..4, zero-padded to 8)
  for (int idx = tid0; idx < 4*64; idx += stride) {
    int i = idx >> 6, l = idx & 63;
    uint4 o; uint* op = (uint*)&o;
    #pragma unroll
    for (int q=0;q<4;++q){
      int j = q*64 + l;
      int k0 = 2*i, k1 = 2*i+1;
      float a = (k0 < 5) ? decWih[j*5 + k0] : 0.f;
      float b = (k1 < 5) ? decWih[j*5 + k1] : 0.f;
      op[q] = pack_rtn(a,b);
    }
    ((uint4*)(ws + WS_DECY2))[idx] = o;
  }
  for (int idx = tid0; idx < 32*64; idx += stride) {
    int ep = idx >> 6, l = idx & 63;
    uint4 o; uint* op = (uint*)&o;
    #pragma unroll
    for (int q=0;q<4;++q){
      int j = q*64 + l;
      op[q] = pack_rtn(decWhh[j*64 + 2*ep], decWhh[j*64 + 2*ep+1]);
    }
    ((uint4*)(ws + WS_DECPK))[idx] = o;
  }
  for (int idx = tid0; idx < 256; idx += stride) {
    int l = idx >> 2, q = idx & 3, j = q*64+l;
    wsf[WS_DECB+idx] = decbih[j] + decbhh[j];
  }
  for (int idx = tid0; idx < 32*64; idx += stride) {
    int ep = idx >> 6, l = idx & 63;
    uint2 o;
    o.x = pack_rtn(w1[l*192 + 2*ep],      w1[l*192 + 2*ep+1]);
    o.y = pack_rtn(w1[l*192 + 64 + 2*ep], w1[l*192 + 64 + 2*ep+1]);
    ((uint2*)(ws + WS_W1HCP))[idx] = o;
  }
  for (int idx = tid0; idx < 32*64; idx += stride) {
    int ep = idx >> 6, l = idx & 63;
    ws[WS_W1XP + idx] = pack_rtn(w1[l*192 + 128 + 2*ep], w1[l*192 + 128 + 2*ep+1]);
  }
}

// MFMA G-producer, coalesced rewrite (R4).
// Phase A (thread=(b,kc)): coalesced x reads, per-thread scores for 8 k's,
//   softmax reduced within 16-lane shfl groups (no LDS, no barrier).
// Phase B: re-read x (L2-warm), wi = rtz(at*x) -> ds_write wiS[t][b][136-pad].
// Phase C: verified R1 MFMA loop; B-frags via ds_read_b128 from wiS.
__global__ __launch_bounds__(256, 2) void gemmG_mfma(
    const float* __restrict__ x, const float* __restrict__ enc_attn_w,
    const float* __restrict__ ws, _Float16* __restrict__ Gh)
{
  const int tid = threadIdx.x;
  const int b0  = blockIdx.x * 16;
  const uint* wsu = (const uint*)ws;

  __shared__ _Float16 wiS[L_][16][136];   // 43520 B

  const int l   = tid & 63;
  const int w   = tid >> 6;
  const int col = l & 15;
  const int g   = l >> 4;

  // ---- A-frag gather (weights, one-time, L2-hot) ----
  f16x8 afr[4][4];
  #pragma unroll
  for (int im=0; im<4; ++im){
    #pragma unroll
    for (int kf=0; kf<4; ++kf){
      U4 cv;
      #pragma unroll
      for (int i=0;i<4;++i){
        int kp = kf*16 + g*4 + i;
        int lsrc = im*16 + col;
        cv.u[i] = wsu[WS_ENCPK + (kp*64 + lsrc)*4 + w];
      }
      afr[im][kf] = cv.v;
    }
  }
  float bias[4][4];
  #pragma unroll
  for (int im=0; im<4; ++im)
    #pragma unroll
    for (int r=0; r<4; ++r)
      bias[im][r] = ws[WS_ENCB + (im*16 + g*4 + r)*4 + w];

  // ---- phase A: coalesced score pass ----
  const int b  = tid >> 4;
  const int kc = tid & 15;
  const float* xb = x + (size_t)(b0+b)*(L_*D_) + kc*8;

  float wxv[L_];
  #pragma unroll
  for (int t=0;t<L_;++t) wxv[t] = enc_attn_w[2*H_ + t];

  float s[8];
  #pragma unroll
  for (int j=0;j<8;++j) s[j]=0.f;
  #pragma unroll
  for (int t=0;t<L_;++t){
    float wx = wxv[t];
    float4 x0 = *(const float4*)(xb + t*D_);
    float4 x1 = *(const float4*)(xb + t*D_ + 4);
    s[0]+=x0.x*wx; s[1]+=x0.y*wx; s[2]+=x0.z*wx; s[3]+=x0.w*wx;
    s[4]+=x1.x*wx; s[5]+=x1.y*wx; s[6]+=x1.z*wx; s[7]+=x1.w*wx;
  }
  float m = s[0];
  #pragma unroll
  for (int j=1;j<8;++j) m = fmaxf(m, s[j]);
  m = fmaxf(m, __shfl_xor(m,1));
  m = fmaxf(m, __shfl_xor(m,2));
  m = fmaxf(m, __shfl_xor(m,4));
  m = fmaxf(m, __shfl_xor(m,8));
  float at[8];
  float ss = 0.f;
  #pragma unroll
  for (int j=0;j<8;++j){ at[j] = __expf(s[j]-m); ss += at[j]; }
  ss += __shfl_xor(ss,1);
  ss += __shfl_xor(ss,2);
  ss += __shfl_xor(ss,4);
  ss += __shfl_xor(ss,8);
  float inv = 1.f/ss;
  #pragma unroll
  for (int j=0;j<8;++j) at[j] *= inv;

  // ---- phase B: wi = rtz(at * x) -> LDS ----
  #pragma unroll
  for (int t=0;t<L_;++t){
    float4 x0 = *(const float4*)(xb + t*D_);
    float4 x1 = *(const float4*)(xb + t*D_ + 4);
    uint4 o;
    o.x = pack_rtz(at[0]*x0.x, at[1]*x0.y);
    o.y = pack_rtz(at[2]*x0.z, at[3]*x0.w);
    o.z = pack_rtz(at[4]*x1.x, at[5]*x1.y);
    o.w = pack_rtz(at[6]*x1.z, at[7]*x1.w);
    *(uint4*)&wiS[t][b][kc*8] = o;
  }
  __syncthreads();

  // ---- phase C: MFMA main loop (B-frags from LDS) ----
  #pragma unroll 2
  for (int t=0;t<L_;++t){
    U4 bu[4];
    #pragma unroll
    for (int kf=0;kf<4;++kf)
      bu[kf].q = *(const uint4*)&wiS[t][col][kf*32 + g*8];
    _Float16* grow = Gh + ((size_t)(b0+col)*L_ + t)*256;
    #pragma unroll
    for (int im=0;im<4;++im){
      f32x4 acc = { bias[im][0], bias[im][1], bias[im][2], bias[im][3] };
      #pragma unroll
      for (int kf=0;kf<4;++kf)
        acc = __builtin_amdgcn_mfma_f32_16x16x32_f16(afr[im][kf], bu[kf].v, acc, 0, 0, 0);
      uint2 o = make_uint2(pack_rtn(acc[0],acc[1]), pack_rtn(acc[2],acc[3]));
      *(uint2*)(grow + (4*w+im)*16 + g*4) = o;
    }
  }
}

// LDS arena offsets (bytes)
#define SM_HXE   0        // uint [2][16][36]            = 4608   (enc only)
#define SM_XES   4608     // f16  [10][16][72]           = 23040  (enc..preC)
#define SM_TMPF  0        // float[10][16][5][4]         = 12800  (fxe phase; aliases HXE/XES)
#define SM_TMPG  12800    // float[10][16][5][4]         = 12800
#define SM_HXD   27648    // uint [2][16][36]            = 4608
#define SM_CXD   32256    // uint [2][16][36]            = 4608
#define SM_SRED  36864    // float[10][16][4]            = 2560
#define SM_FXE   39424    // float[16][10][5]            = 3200
#define SM_GXE   42624    // float[16][10][5]            = 3200
#define SM_YBS   45824    // float[16][50]               = 3200
#define SM_TOTAL 49024

// Cooperative darnn (R3 body, unchanged this round).
__global__ __launch_bounds__(256, 2) void darnn_kernel(
    const float* __restrict__ y_hist,
    const float* __restrict__ h0e, const float* __restrict__ c0e,
    const float* __restrict__ h0d, const float* __restrict__ c0d,
    const float* __restrict__ dec_attn_b1, const float* __restrict__ dec_attn_w2,
    const float* __restrict__ fc_w, const float* __restrict__ fc_b,
    const float* __restrict__ fcout_w, const float* __restrict__ fcout_b,
    const float* __restrict__ ws, const uint2* __restrict__ Gp,
    float* __restrict__ out)
{
  const int tid = threadIdx.x;
  const int l   = tid & 63;
  const int w   = tid >> 6;
  const int col = l & 15;
  const int g   = l >> 4;
  const int b0  = blockIdx.x * 16;
  const int lw  = 16*w + col;
  const int u0  = 16*w + 4*g;

  const uint* wsu = (const uint*)ws;
  const _Float16* Gh = (const _Float16*)Gp;

  __shared__ __align__(16) char smem_[SM_TOTAL];
  uint     (*hxE)[16][36] = reinterpret_cast<uint(*)[16][36]>(smem_ + SM_HXE);
  _Float16 (*xeS)[16][72] = reinterpret_cast<_Float16(*)[16][72]>(smem_ + SM_XES);
  float* tmpF = (float*)(smem_ + SM_TMPF);
  float* tmpG = (float*)(smem_ + SM_TMPG);
  uint     (*hxD)[16][36] = reinterpret_cast<uint(*)[16][36]>(smem_ + SM_HXD);
  uint     (*cxD)[16][36] = reinterpret_cast<uint(*)[16][36]>(smem_ + SM_CXD);
  float* sred = (float*)(smem_ + SM_SRED);
  float* fxeS = (float*)(smem_ + SM_FXE);
  float* gxeS = (float*)(smem_ + SM_GXE);
  float* ybS  = (float*)(smem_ + SM_YBS);

  const bool yact = (tid < 200);
  if (yact){
    float4 yreg = *(const float4*)(y_hist + (size_t)b0*50 + tid*4);
    *(float4*)(ybS + tid*4) = yreg;
  }
  float4 hd4 = *(const float4*)(h0d + (size_t)(b0+col)*64 + u0);
  float4 cd4 = *(const float4*)(c0d + (size_t)(b0+col)*64 + u0);

  f16x8 aE[4][2];
  #pragma unroll
  for (int q=0;q<4;++q)
    #pragma unroll
    for (int kf=0;kf<2;++kf){
      U4 cv;
      #pragma unroll
      for (int i=0;i<4;++i)
        cv.u[i] = wsu[WS_ENCPK + ((64 + kf*16 + g*4 + i)*64 + lw)*4 + q];
      aE[q][kf] = cv.v;
    }

  float h[4], c[4], xer[L_][4];
  {
    float4 hv = *(const float4*)(h0e + (size_t)(b0+col)*64 + u0);
    float4 cv = *(const float4*)(c0e + (size_t)(b0+col)*64 + u0);
    h[0]=hv.x; h[1]=hv.y; h[2]=hv.z; h[3]=hv.w;
    c[0]=cv.x; c[1]=cv.y; c[2]=cv.z; c[3]=cv.w;
  }
  *(uint2*)&hxE[0][col][u0>>1] = make_uint2(pack_rtz(h[0],h[1]), pack_rtz(h[2],h[3]));
  __syncthreads();

  uint2 gq[2][4];
  {
    const _Float16* g0 = Gh + ((size_t)(b0+col)*L_ + 0)*256;
    const _Float16* g1 = Gh + ((size_t)(b0+col)*L_ + 1)*256;
    #pragma unroll
    for (int q=0;q<4;++q){
      gq[0][q] = *(const uint2*)(g0 + q*64 + u0);
      gq[1][q] = *(const uint2*)(g1 + q*64 + u0);
    }
  }

  int p = 0;
  for (int t=0; t<L_; ++t){
    const int cb = t&1;
    f32x4 acc[4];
    #pragma unroll
    for (int q=0;q<4;++q){
      float2 u0f = unpk(gq[cb][q].x), u1f = unpk(gq[cb][q].y);
      acc[q][0]=u0f.x; acc[q][1]=u0f.y; acc[q][2]=u1f.x; acc[q][3]=u1f.y;
    }
    if (t+2<L_){
      const _Float16* gn = Gh + ((size_t)(b0+col)*L_ + (t+2))*256;
      #pragma unroll
      for (int q=0;q<4;++q) gq[cb][q] = *(const uint2*)(gn + q*64 + u0);
    }
    f16x8 hB[2];
    { U4 t0; t0.q = *(const uint4*)&hxE[p][col][g*4];      hB[0]=t0.v; }
    { U4 t1; t1.q = *(const uint4*)&hxE[p][col][16 + g*4]; hB[1]=t1.v; }

    #pragma unroll
    for (int q=0;q<4;++q){
      acc[q] = __builtin_amdgcn_mfma_f32_16x16x32_f16(aE[q][0], hB[0], acc[q], 0,0,0);
      acc[q] = __builtin_amdgcn_mfma_f32_16x16x32_f16(aE[q][1], hB[1], acc[q], 0,0,0);
    }
    #pragma unroll
    for (int r=0;r<4;++r){
      float ig=sigmf(acc[0][r]), fg=sigmf(acc[1][r]), gg=tanhf_(acc[2][r]), og=sigmf(acc[3][r]);
      c[r]=fg*c[r]+ig*gg;
      h[r]=og*tanhf_(c[r]);
      xer[t][r]=h[r];
    }
    uint2 hpk = make_uint2(pack_rtz(h[0],h[1]), pack_rtz(h[2],h[3]));
    *(uint2*)&xeS[t][col][u0] = hpk;
    *(uint2*)&hxE[p^1][col][u0>>1] = hpk;
    __syncthreads();
    p ^= 1;
  }

  f16x8 aX[2];
  #pragma unroll
  for (int kf=0;kf<2;++kf){
    U4 cv;
    #pragma unroll
    for (int i=0;i<4;++i) cv.u[i] = wsu[WS_W1XP + (kf*16 + g*4 + i)*64 + lw];
    aX[kf] = cv.v;
  }
  f32x4 preC[L_];
  #pragma unroll
  for (int lt=0;lt<L_;++lt){
    f32x4 a = {0.f,0.f,0.f,0.f};
    U4 bu0, bu1;
    bu0.q = *(const uint4*)&xeS[lt][col][g*8];
    bu1.q = *(const uint4*)&xeS[lt][col][32 + g*8];
    a = __builtin_amdgcn_mfma_f32_16x16x32_f16(aX[0], bu0.v, a, 0,0,0);
    a = __builtin_amdgcn_mfma_f32_16x16x32_f16(aX[1], bu1.v, a, 0,0,0);
    preC[lt] = a;
  }
  __syncthreads();

  {
    float fw1v[OUT_][4], gw1v[OUT_][4];
    #pragma unroll
    for (int o2=0;o2<OUT_;++o2)
      #pragma unroll
      for (int r=0;r<4;++r){
        fw1v[o2][r] = fc_w[o2*69 + u0 + r];
        gw1v[o2][r] = fcout_w[o2*128 + 64 + u0 + r];
      }
    #pragma unroll
    for (int lt=0;lt<L_;++lt){
      #pragma unroll
      for (int o2=0;o2<OUT_;++o2){
        float pf = fw1v[o2][0]*xer[lt][0] + fw1v[o2][1]*xer[lt][1]
                 + fw1v[o2][2]*xer[lt][2] + fw1v[o2][3]*xer[lt][3];
        float pg = gw1v[o2][0]*xer[lt][0] + gw1v[o2][1]*xer[lt][1]
                 + gw1v[o2][2]*xer[lt][2] + gw1v[o2][3]*xer[lt][3];
        pf += __shfl_xor(pf,16); pf += __shfl_xor(pf,32);
        pg += __shfl_xor(pg,16); pg += __shfl_xor(pg,32);
        if (g==0){
          tmpF[((lt*16+col)*OUT_+o2)*4 + w] = pf;
          tmpG[((lt*16+col)*OUT_+o2)*4 + w] = pg;
        }
      }
    }
  }
  __syncthreads();
  for (int idx=tid; idx<800; idx+=256){
    float4 f4 = *(const float4*)(tmpF + idx*4);
    float4 g4 = *(const float4*)(tmpG + idx*4);
    int o2 = idx % 5, rest = idx / 5;
    int b  = rest % 16, lt = rest / 16;
    fxeS[b*50 + lt*5 + o2] = f4.x+f4.y+f4.z+f4.w;
    gxeS[b*50 + lt*5 + o2] = g4.x+g4.y+g4.z+g4.w;
  }

  f16x8 aW1[4];
  #pragma unroll
  for (int kf=0;kf<4;++kf){
    U4 cv;
    #pragma unroll
    for (int i=0;i<4;++i){
      int ep = (kf&1)*16 + g*4 + i;
      cv.u[i] = wsu[WS_W1HCP + (ep*64 + lw)*2 + (kf>>1)];
    }
    aW1[kf] = cv.v;
  }
  f16x8 aGh[4][2];
  #pragma unroll
  for (int q=0;q<4;++q)
    #pragma unroll
    for (int kf=0;kf<2;++kf){
      U4 cv;
      #pragma unroll
      for (int i=0;i<4;++i)
        cv.u[i] = wsu[WS_DECPK + ((kf*16 + g*4 + i)*64 + lw)*4 + q];
      aGh[q][kf] = cv.v;
    }
  f16x8 aG0[4];
  #pragma unroll
  for (int q=0;q<4;++q){
    U4 cv;
    #pragma unroll
    for (int i=0;i<4;++i)
      cv.u[i] = (g==0) ? wsu[WS_DECY2 + (i*64 + lw)*4 + q] : 0u;
    aG0[q] = cv.v;
  }
  float4 bD[4];
  #pragma unroll
  for (int r=0;r<4;++r) bD[r] = *(const float4*)(ws + WS_DECB + (u0+r)*4);
  float4 b1v = *(const float4*)(dec_attn_b1 + u0);
  float4 w2v = *(const float4*)(dec_attn_w2 + u0);
  float fcbv[OUT_], fw2v[OUT_][OUT_];
  #pragma unroll
  for (int o2=0;o2<OUT_;++o2){
    fcbv[o2] = fc_b[o2];
    #pragma unroll
    for (int j=0;j<OUT_;++j) fw2v[o2][j] = fc_w[o2*69 + 64 + j];
  }

  h[0]=hd4.x; h[1]=hd4.y; h[2]=hd4.z; h[3]=hd4.w;
  c[0]=cd4.x; c[1]=cd4.y; c[2]=cd4.z; c[3]=cd4.w;
  *(uint2*)&hxD[0][col][u0>>1] = make_uint2(pack_rtz(h[0],h[1]), pack_rtz(h[2],h[3]));
  *(uint2*)&cxD[0][col][u0>>1] = make_uint2(pack_rtz(c[0],c[1]), pack_rtz(c[2],c[3]));
  __syncthreads();

  float at[L_];
  float inv = 0.f;
  p = 0;
  for (int t=0; t<L_; ++t){
    f16x8 hB[2], cB[2];
    { U4 t0; t0.q = *(const uint4*)&hxD[p][col][g*4];      hB[0]=t0.v; }
    { U4 t1; t1.q = *(const uint4*)&hxD[p][col][16 + g*4]; hB[1]=t1.v; }
    { U4 t2; t2.q = *(const uint4*)&cxD[p][col][g*4];      cB[0]=t2.v; }
    { U4 t3; t3.q = *(const uint4*)&cxD[p][col][16 + g*4]; cB[1]=t3.v; }

    f32x4 vb = { b1v.x, b1v.y, b1v.z, b1v.w };
    vb = __builtin_amdgcn_mfma_f32_16x16x32_f16(aW1[0], hB[0], vb, 0,0,0);
    vb = __builtin_amdgcn_mfma_f32_16x16x32_f16(aW1[1], hB[1], vb, 0,0,0);
    vb = __builtin_amdgcn_mfma_f32_16x16x32_f16(aW1[2], cB[0], vb, 0,0,0);
    vb = __builtin_amdgcn_mfma_f32_16x16x32_f16(aW1[3], cB[1], vb, 0,0,0);

    #pragma unroll
    for (int lt=0;lt<L_;++lt){
      float zp = tanhf_(preC[lt][0] + vb[0]) * w2v.x
               + tanhf_(preC[lt][1] + vb[1]) * w2v.y
               + tanhf_(preC[lt][2] + vb[2]) * w2v.z
               + tanhf_(preC[lt][3] + vb[3]) * w2v.w;
      zp += __shfl_xor(zp,16);
      zp += __shfl_xor(zp,32);
      at[lt] = zp;
    }
    if (g==0){
      #pragma unroll
      for (int lt=0;lt<L_;++lt) sred[(lt*16+col)*4 + w] = at[lt];
    }
    __syncthreads();
    #pragma unroll
    for (int lt=0;lt<L_;++lt){
      float4 s4 = *(const float4*)(sred + (lt*16+col)*4);
      at[lt] = s4.x + s4.y + s4.z + s4.w;
    }
    float mx = at[0];
    #pragma unroll
    for (int lt=1;lt<L_;++lt) mx = fmaxf(mx, at[lt]);
    float ssum = 0.f;
    #pragma unroll
    for (int lt=0;lt<L_;++lt){ at[lt] = __expf(at[lt]-mx); ssum += at[lt]; }
    inv = 1.f/ssum;

    U4 ycv; ycv.u[0]=0u; ycv.u[1]=0u; ycv.u[2]=0u; ycv.u[3]=0u;
    if (g==0){
      const float* fx = fxeS + col*50;
      const float* yb = ybS + col*50 + t*5;
      float yt[OUT_];
      #pragma unroll
      for (int o2=0;o2<OUT_;++o2){
        float s = 0.f;
        #pragma unroll
        for (int lt=0;lt<L_;++lt) s += at[lt]*fx[lt*5+o2];
        float v = s*inv + fcbv[o2];
        #pragma unroll
        for (int j=0;j<OUT_;++j) v += yb[j]*fw2v[o2][j];
        yt[o2] = v;
      }
      ycv.u[0] = pack_rtn(yt[0], yt[1]);
      ycv.u[1] = pack_rtn(yt[2], yt[3]);
      ycv.u[2] = pack_rtn(yt[4], 0.f);
    }
    f32x4 accQ[4];
    #pragma unroll
    for (int q=0;q<4;++q){
      accQ[q][0]=((const float*)&bD[0])[q];
      accQ[q][1]=((const float*)&bD[1])[q];
      accQ[q][2]=((const float*)&bD[2])[q];
      accQ[q][3]=((const float*)&bD[3])[q];
    }
    #pragma unroll
    for (int q=0;q<4;++q){
      accQ[q] = __builtin_amdgcn_mfma_f32_16x16x32_f16(aG0[q], ycv.v, accQ[q], 0,0,0);
      accQ[q] = __builtin_amdgcn_mfma_f32_16x16x32_f16(aGh[q][0], hB[0], accQ[q], 0,0,0);
      accQ[q] = __builtin_amdgcn_mfma_f32_16x16x32_f16(aGh[q][1], hB[1], accQ[q], 0,0,0);
    }
    #pragma unroll
    for (int r=0;r<4;++r){
      float ig=sigmf(accQ[0][r]), fg=sigmf(accQ[1][r]), gg=tanhf_(accQ[2][r]), og=sigmf(accQ[3][r]);
      c[r]=fg*c[r]+ig*gg;
      h[r]=og*tanhf_(c[r]);
    }
    *(uint2*)&hxD[p^1][col][u0>>1] = make_uint2(pack_rtz(h[0],h[1]), pack_rtz(h[2],h[3]));
    *(uint2*)&cxD[p^1][col][u0>>1] = make_uint2(pack_rtz(c[0],c[1]), pack_rtz(c[2],c[3]));
    __syncthreads();
    p ^= 1;
  }

  {
    float fcA[OUT_][4];
    #pragma unroll
    for (int o2=0;o2<OUT_;++o2)
      #pragma unroll
      for (int r=0;r<4;++r) fcA[o2][r] = fcout_w[o2*128 + u0 + r];
    #pragma unroll
    for (int o2=0;o2<OUT_;++o2){
      float pv = fcA[o2][0]*h[0] + fcA[o2][1]*h[1] + fcA[o2][2]*h[2] + fcA[o2][3]*h[3];
      pv += __shfl_xor(pv,16);
      pv += __shfl_xor(pv,32);
      if (g==0) sred[(o2*16+col)*4 + w] = pv;
    }
  }
  __syncthreads();
  if (w==0 && g==0){
    const float* gx = gxeS + col*50;
    #pragma unroll
    for (int o2=0;o2<OUT_;++o2){
      float4 s4 = *(const float4*)(sred + (o2*16+col)*4);
      float s = 0.f;
      #pragma unroll
      for (int lt=0;lt<L_;++lt) s += at[lt]*gx[lt*5+o2];
      out[(size_t)(b0+col)*OUT_ + o2] = s4.x+s4.y+s4.z+s4.w + s*inv + fcout_b[o2];
    }
  }
}

extern "C" void kernel_launch(void* const* d_in, const int* in_sizes, int n_in,
                              void* d_out, int out_size, void* d_ws, size_t ws_size,
                              hipStream_t stream) {
  const float* x          = (const float*)d_in[0];
  const float* y_hist     = (const float*)d_in[1];
  const float* h0_enc     = (const float*)d_in[2];
  const float* c0_enc     = (const float*)d_in[3];
  const float* h0_dec     = (const float*)d_in[4];
  const float* c0_dec     = (const float*)d_in[5];
  const float* enc_attn_w = (const float*)d_in[6];
  const float* enc_Wih    = (const float*)d_in[8];
  const float* enc_Whh    = (const float*)d_in[9];
  const float* enc_bih    = (const float*)d_in[10];
  const float* enc_bhh    = (const float*)d_in[11];
  const float* dec_attn_w1= (const float*)d_in[12];
  const float* dec_attn_b1= (const float*)d_in[13];
  const float* dec_attn_w2= (const float*)d_in[14];
  const float* dec_Wih    = (const float*)d_in[16];
  const float* dec_Whh    = (const float*)d_in[17];
  const float* dec_bih    = (const float*)d_in[18];
  const float* dec_bhh    = (const float*)d_in[19];
  const float* fc_w       = (const float*)d_in[20];
  const float* fc_b       = (const float*)d_in[21];
  const float* fcout_w    = (const float*)d_in[22];
  const float* fcout_b    = (const float*)d_in[23];
  float* ws = (float*)d_ws;
  float* out = (float*)d_out;
  uint2* Gp = (uint2*)((uint*)d_ws + WS_G);

  hipLaunchKernelGGL(prep_kernel, dim3(128), dim3(256), 0, stream,
                     enc_Wih, enc_Whh, enc_bih, enc_bhh,
                     dec_Wih, dec_Whh, dec_bih, dec_bhh,
                     dec_attn_w1, ws);
  hipLaunchKernelGGL(gemmG_mfma, dim3(B_/16), dim3(256), 0, stream,
                     x, enc_attn_w, ws, (_Float16*)Gp);
  hipLaunchKernelGGL(darnn_kernel, dim3(B_/16), dim3(256), 0, stream,
                     y_hist, h0_enc, c0_enc, h0_dec, c0_dec,
                     dec_attn_b1, dec_attn_w2,
                     fc_w, fc_b, fcout_w, fcout_b, ws, Gp, out);
}

// Round 5
// 220.626 us; speedup vs baseline: 1.2861x; 1.1508x over previous
//
#include <hip/hip_runtime.h>

// Problem constants
#define B_  8192
#define L_  10
#define D_  128
#define H_  64
#define OUT_ 5

typedef _Float16 h2 __attribute__((ext_vector_type(2)));
typedef _Float16 f16x8 __attribute__((ext_vector_type(8)));
typedef float f32x4 __attribute__((ext_vector_type(4)));
typedef unsigned int uint;

// ws dword layout:
#define WS_ENCPK   0        // [kp<96][l]: uint4, dword q = half2(W[q*64+l][2kp], [2kp+1]); k<128: Wih, else Whh
#define WS_ENCB    24576    // 256 floats: [l][q] = bih+bhh
#define WS_DECY2   24832    // [i<4][l<64]: uint4, comp q = half2(decWih[q*64+l][2i], [2i+1]) zero-padded k>=5
#define WS_DECPK   26112    // [ep<32][l]: uint4, half2(decWhh[q*64+l][2ep], [2ep+1])
#define WS_DECB    34304    // 256 floats: [u][q]
#define WS_W1HCP   34560    // [ep<32][l]: uint2 {half2 W1h pair, half2 W1c pair}
#define WS_W1XP    38656    // [ep<32][l]: uint half2 W1x pair

__device__ __forceinline__ float sigmf(float x){ return 1.f/(1.f+__expf(-x)); }
__device__ __forceinline__ float tanhf_(float x){ return 1.f - 2.f/(1.f+__expf(2.f*x)); }
__device__ __forceinline__ uint pack_rtz(float a, float b){
  return __builtin_bit_cast(uint, __builtin_amdgcn_cvt_pkrtz(a, b));
}
__device__ __forceinline__ uint pack_rtn(float a, float b){
  h2 v; v.x = (_Float16)a; v.y = (_Float16)b;
  return __builtin_bit_cast(uint, v);
}
__device__ __forceinline__ float2 unpk(uint u){
  h2 v = __builtin_bit_cast(h2, u);
  return make_float2((float)v.x, (float)v.y);
}

union U4 { uint u[4]; uint4 q; f16x8 v; };

__global__ void prep_kernel(const float* __restrict__ encWih, const float* __restrict__ encWhh,
                            const float* __restrict__ encbih, const float* __restrict__ encbhh,
                            const float* __restrict__ decWih, const float* __restrict__ decWhh,
                            const float* __restrict__ decbih, const float* __restrict__ decbhh,
                            const float* __restrict__ w1, float* __restrict__ wsf)
{
  uint* ws = (uint*)wsf;
  int stride = gridDim.x * blockDim.x;
  int tid0 = blockIdx.x * blockDim.x + threadIdx.x;

  for (int idx = tid0; idx < 96*64; idx += stride) {
    int kp = idx >> 6, l = idx & 63;
    uint4 o; uint* op = (uint*)&o;
    #pragma unroll
    for (int q=0;q<4;++q){
      int j = q*64 + l;
      int k0 = 2*kp, k1 = 2*kp+1;
      float a = (k0 < 128) ? encWih[j*128 + k0] : encWhh[j*64 + (k0-128)];
      float b = (k1 < 128) ? encWih[j*128 + k1] : encWhh[j*64 + (k1-128)];
      op[q] = pack_rtn(a,b);
    }
    ((uint4*)(ws + WS_ENCPK))[idx] = o;
  }
  for (int idx = tid0; idx < 256; idx += stride) {
    int l = idx >> 2, q = idx & 3, j = q*64+l;
    wsf[WS_ENCB+idx] = encbih[j] + encbhh[j];
  }
  // dec Wih packed for MFMA kf0 (k = 0..4, zero-padded to 8)
  for (int idx = tid0; idx < 4*64; idx += stride) {
    int i = idx >> 6, l = idx & 63;
    uint4 o; uint* op = (uint*)&o;
    #pragma unroll
    for (int q=0;q<4;++q){
      int j = q*64 + l;
      int k0 = 2*i, k1 = 2*i+1;
      float a = (k0 < 5) ? decWih[j*5 + k0] : 0.f;
      float b = (k1 < 5) ? decWih[j*5 + k1] : 0.f;
      op[q] = pack_rtn(a,b);
    }
    ((uint4*)(ws + WS_DECY2))[idx] = o;
  }
  for (int idx = tid0; idx < 32*64; idx += stride) {
    int ep = idx >> 6, l = idx & 63;
    uint4 o; uint* op = (uint*)&o;
    #pragma unroll
    for (int q=0;q<4;++q){
      int j = q*64 + l;
      op[q] = pack_rtn(decWhh[j*64 + 2*ep], decWhh[j*64 + 2*ep+1]);
    }
    ((uint4*)(ws + WS_DECPK))[idx] = o;
  }
  for (int idx = tid0; idx < 256; idx += stride) {
    int l = idx >> 2, q = idx & 3, j = q*64+l;
    wsf[WS_DECB+idx] = decbih[j] + decbhh[j];
  }
  for (int idx = tid0; idx < 32*64; idx += stride) {
    int ep = idx >> 6, l = idx & 63;
    uint2 o;
    o.x = pack_rtn(w1[l*192 + 2*ep],      w1[l*192 + 2*ep+1]);
    o.y = pack_rtn(w1[l*192 + 64 + 2*ep], w1[l*192 + 64 + 2*ep+1]);
    ((uint2*)(ws + WS_W1HCP))[idx] = o;
  }
  for (int idx = tid0; idx < 32*64; idx += stride) {
    int ep = idx >> 6, l = idx & 63;
    ws[WS_W1XP + idx] = pack_rtn(w1[l*192 + 128 + 2*ep], w1[l*192 + 128 + 2*ep+1]);
  }
}

// LDS arena offsets (bytes). wiS (G-phase, 43520 B) aliases [0..43520) and is
// dead before any aliased darnn region is written. ybS at 45824 does NOT
// overlap wiS, so y_hist staging can run before the G phase.
#define SM_HXE   0        // uint [2][16][36]            = 4608   (enc only)
#define SM_XES   4608     // f16  [10][16][72]           = 23040  (enc..preC)
#define SM_TMPF  0        // float[10][16][5][4]         = 12800  (fxe phase; aliases HXE/XES)
#define SM_TMPG  12800    // float[10][16][5][4]         = 12800
#define SM_HXD   27648    // uint [2][16][36]            = 4608
#define SM_CXD   32256    // uint [2][16][36]            = 4608
#define SM_SRED  36864    // float[10][16][4]            = 2560
#define SM_FXE   39424    // float[16][10][5]            = 3200
#define SM_GXE   42624    // float[16][10][5]            = 3200
#define SM_YBS   45824    // float[16][50]               = 3200
#define SM_TOTAL 49024

// Fused kernel: G-phase (coalesced scores + wi->LDS + MFMA, gate-quadrant tile
// mapping so each lane's accumulator IS its encoder gq) + cooperative darnn.
// G never touches global memory.
__global__ __launch_bounds__(256, 2) void darnn_fused(
    const float* __restrict__ x, const float* __restrict__ enc_attn_w,
    const float* __restrict__ y_hist,
    const float* __restrict__ h0e, const float* __restrict__ c0e,
    const float* __restrict__ h0d, const float* __restrict__ c0d,
    const float* __restrict__ dec_attn_b1, const float* __restrict__ dec_attn_w2,
    const float* __restrict__ fc_w, const float* __restrict__ fc_b,
    const float* __restrict__ fcout_w, const float* __restrict__ fcout_b,
    const float* __restrict__ ws,
    float* __restrict__ out)
{
  const int tid = threadIdx.x;
  const int l   = tid & 63;
  const int w   = tid >> 6;
  const int col = l & 15;          // batch sub-row (MFMA col)
  const int g   = l >> 4;          // k-group / C-row group
  const int b0  = blockIdx.x * 16;
  const int lw  = 16*w + col;      // row into 64-wide weight tables
  const int u0  = 16*w + 4*g;      // first hidden-unit of this lane's slice

  const uint* wsu = (const uint*)ws;

  __shared__ __align__(16) char smem_[SM_TOTAL];
  _Float16 (*wiS)[16][136] = reinterpret_cast<_Float16(*)[16][136]>(smem_);   // G-phase alias
  uint     (*hxE)[16][36] = reinterpret_cast<uint(*)[16][36]>(smem_ + SM_HXE);
  _Float16 (*xeS)[16][72] = reinterpret_cast<_Float16(*)[16][72]>(smem_ + SM_XES);
  float* tmpF = (float*)(smem_ + SM_TMPF);
  float* tmpG = (float*)(smem_ + SM_TMPG);
  uint     (*hxD)[16][36] = reinterpret_cast<uint(*)[16][36]>(smem_ + SM_HXD);
  uint     (*cxD)[16][36] = reinterpret_cast<uint(*)[16][36]>(smem_ + SM_CXD);
  float* sred = (float*)(smem_ + SM_SRED);
  float* fxeS = (float*)(smem_ + SM_FXE);
  float* gxeS = (float*)(smem_ + SM_GXE);
  float* ybS  = (float*)(smem_ + SM_YBS);

  // ---- early loads whose latency hides under the G phase ----
  if (tid < 200){
    float4 yreg = *(const float4*)(y_hist + (size_t)b0*50 + tid*4);
    *(float4*)(ybS + tid*4) = yreg;   // ybS does not alias wiS
  }
  float4 hd4 = *(const float4*)(h0d + (size_t)(b0+col)*64 + u0);
  float4 cd4 = *(const float4*)(c0d + (size_t)(b0+col)*64 + u0);
  float4 he4 = *(const float4*)(h0e + (size_t)(b0+col)*64 + u0);
  float4 ce4 = *(const float4*)(c0e + (size_t)(b0+col)*64 + u0);

  // =========================== G phase ===========================
  // A-frags with GATE-QUADRANT tiles: tile im covers j = im*64 + 16w + [0,16)
  // -> lane (w,col,g) accumulator rows r give j = im*64 + 16w + 4g + r,
  //    batch = b0+col : exactly the encoder's gq[t][im] values.
  f16x8 afr[4][4];
  #pragma unroll
  for (int im=0; im<4; ++im){
    #pragma unroll
    for (int kf=0; kf<4; ++kf){
      U4 cv;
      #pragma unroll
      for (int i=0;i<4;++i){
        int kp = kf*16 + g*4 + i;
        cv.u[i] = wsu[WS_ENCPK + (kp*64 + lw)*4 + im];
      }
      afr[im][kf] = cv.v;
    }
  }
  float bias[4][4];
  #pragma unroll
  for (int im=0; im<4; ++im)
    #pragma unroll
    for (int r=0; r<4; ++r)
      bias[im][r] = ws[WS_ENCB + (u0 + r)*4 + im];

  // phase A: coalesced score pass (thread = (b, kc))
  const int bb = tid >> 4;
  const int kc = tid & 15;
  const float* xb = x + (size_t)(b0+bb)*(L_*D_) + kc*8;

  float wxv[L_];
  #pragma unroll
  for (int t=0;t<L_;++t) wxv[t] = enc_attn_w[2*H_ + t];

  float s[8];
  #pragma unroll
  for (int j=0;j<8;++j) s[j]=0.f;
  #pragma unroll
  for (int t=0;t<L_;++t){
    float wx = wxv[t];
    float4 x0 = *(const float4*)(xb + t*D_);
    float4 x1 = *(const float4*)(xb + t*D_ + 4);
    s[0]+=x0.x*wx; s[1]+=x0.y*wx; s[2]+=x0.z*wx; s[3]+=x0.w*wx;
    s[4]+=x1.x*wx; s[5]+=x1.y*wx; s[6]+=x1.z*wx; s[7]+=x1.w*wx;
  }
  float m = s[0];
  #pragma unroll
  for (int j=1;j<8;++j) m = fmaxf(m, s[j]);
  m = fmaxf(m, __shfl_xor(m,1));
  m = fmaxf(m, __shfl_xor(m,2));
  m = fmaxf(m, __shfl_xor(m,4));
  m = fmaxf(m, __shfl_xor(m,8));
  float atw[8];
  float ss = 0.f;
  #pragma unroll
  for (int j=0;j<8;++j){ atw[j] = __expf(s[j]-m); ss += atw[j]; }
  ss += __shfl_xor(ss,1);
  ss += __shfl_xor(ss,2);
  ss += __shfl_xor(ss,4);
  ss += __shfl_xor(ss,8);
  float ainv = 1.f/ss;
  #pragma unroll
  for (int j=0;j<8;++j) atw[j] *= ainv;

  // phase B: wi = rtz(at * x) -> LDS
  #pragma unroll
  for (int t=0;t<L_;++t){
    float4 x0 = *(const float4*)(xb + t*D_);
    float4 x1 = *(const float4*)(xb + t*D_ + 4);
    uint4 o;
    o.x = pack_rtz(atw[0]*x0.x, atw[1]*x0.y);
    o.y = pack_rtz(atw[2]*x0.z, atw[3]*x0.w);
    o.z = pack_rtz(atw[4]*x1.x, atw[5]*x1.y);
    o.w = pack_rtz(atw[6]*x1.z, atw[7]*x1.w);
    *(uint4*)&wiS[t][bb][kc*8] = o;
  }
  __syncthreads();

  // phase C: gq[t][im] = f16-packed input gates (registers, never stored)
  uint2 gq[L_][4];
  #pragma unroll
  for (int t=0;t<L_;++t){
    U4 bu[4];
    #pragma unroll
    for (int kf=0;kf<4;++kf)
      bu[kf].q = *(const uint4*)&wiS[t][col][kf*32 + g*8];
    #pragma unroll
    for (int im=0;im<4;++im){
      f32x4 acc = { bias[im][0], bias[im][1], bias[im][2], bias[im][3] };
      #pragma unroll
      for (int kf=0;kf<4;++kf)
        acc = __builtin_amdgcn_mfma_f32_16x16x32_f16(afr[im][kf], bu[kf].v, acc, 0, 0, 0);
      gq[t][im] = make_uint2(pack_rtn(acc[0],acc[1]), pack_rtn(acc[2],acc[3]));
    }
  }
  __syncthreads();   // wiS dead; darnn arena may now be written

  // =========================== darnn body ===========================
  f16x8 aE[4][2];
  #pragma unroll
  for (int q=0;q<4;++q)
    #pragma unroll
    for (int kf=0;kf<2;++kf){
      U4 cv;
      #pragma unroll
      for (int i=0;i<4;++i)
        cv.u[i] = wsu[WS_ENCPK + ((64 + kf*16 + g*4 + i)*64 + lw)*4 + q];
      aE[q][kf] = cv.v;
    }

  float h[4], c[4], xer[L_][4];
  h[0]=he4.x; h[1]=he4.y; h[2]=he4.z; h[3]=he4.w;
  c[0]=ce4.x; c[1]=ce4.y; c[2]=ce4.z; c[3]=ce4.w;
  *(uint2*)&hxE[0][col][u0>>1] = make_uint2(pack_rtz(h[0],h[1]), pack_rtz(h[2],h[3]));
  __syncthreads();

  int p = 0;
  #pragma unroll
  for (int t=0; t<L_; ++t){
    f32x4 acc[4];
    #pragma unroll
    for (int q=0;q<4;++q){
      float2 u0f = unpk(gq[t][q].x), u1f = unpk(gq[t][q].y);
      acc[q][0]=u0f.x; acc[q][1]=u0f.y; acc[q][2]=u1f.x; acc[q][3]=u1f.y;
    }
    f16x8 hB[2];
    { U4 t0; t0.q = *(const uint4*)&hxE[p][col][g*4];      hB[0]=t0.v; }
    { U4 t1; t1.q = *(const uint4*)&hxE[p][col][16 + g*4]; hB[1]=t1.v; }

    #pragma unroll
    for (int q=0;q<4;++q){
      acc[q] = __builtin_amdgcn_mfma_f32_16x16x32_f16(aE[q][0], hB[0], acc[q], 0,0,0);
      acc[q] = __builtin_amdgcn_mfma_f32_16x16x32_f16(aE[q][1], hB[1], acc[q], 0,0,0);
    }
    #pragma unroll
    for (int r=0;r<4;++r){
      float ig=sigmf(acc[0][r]), fg=sigmf(acc[1][r]), gg=tanhf_(acc[2][r]), og=sigmf(acc[3][r]);
      c[r]=fg*c[r]+ig*gg;
      h[r]=og*tanhf_(c[r]);
      xer[t][r]=h[r];
    }
    uint2 hpk = make_uint2(pack_rtz(h[0],h[1]), pack_rtz(h[2],h[3]));
    *(uint2*)&xeS[t][col][u0] = hpk;
    *(uint2*)&hxE[p^1][col][u0>>1] = hpk;
    __syncthreads();
    p ^= 1;
  }

  // pre = xe @ W1x^T
  f16x8 aX[2];
  #pragma unroll
  for (int kf=0;kf<2;++kf){
    U4 cv;
    #pragma unroll
    for (int i=0;i<4;++i) cv.u[i] = wsu[WS_W1XP + (kf*16 + g*4 + i)*64 + lw];
    aX[kf] = cv.v;
  }
  f32x4 preC[L_];
  #pragma unroll
  for (int lt=0;lt<L_;++lt){
    f32x4 a = {0.f,0.f,0.f,0.f};
    U4 bu0, bu1;
    bu0.q = *(const uint4*)&xeS[lt][col][g*8];
    bu1.q = *(const uint4*)&xeS[lt][col][32 + g*8];
    a = __builtin_amdgcn_mfma_f32_16x16x32_f16(aX[0], bu0.v, a, 0,0,0);
    a = __builtin_amdgcn_mfma_f32_16x16x32_f16(aX[1], bu1.v, a, 0,0,0);
    preC[lt] = a;
  }
  __syncthreads();   // xeS reads complete before temp overwrite

  // fxe/gxe precompute (f32-exact from xer)
  {
    float fw1v[OUT_][4], gw1v[OUT_][4];
    #pragma unroll
    for (int o2=0;o2<OUT_;++o2)
      #pragma unroll
      for (int r=0;r<4;++r){
        fw1v[o2][r] = fc_w[o2*69 + u0 + r];
        gw1v[o2][r] = fcout_w[o2*128 + 64 + u0 + r];
      }
    #pragma unroll
    for (int lt=0;lt<L_;++lt){
      #pragma unroll
      for (int o2=0;o2<OUT_;++o2){
        float pf = fw1v[o2][0]*xer[lt][0] + fw1v[o2][1]*xer[lt][1]
                 + fw1v[o2][2]*xer[lt][2] + fw1v[o2][3]*xer[lt][3];
        float pg = gw1v[o2][0]*xer[lt][0] + gw1v[o2][1]*xer[lt][1]
                 + gw1v[o2][2]*xer[lt][2] + gw1v[o2][3]*xer[lt][3];
        pf += __shfl_xor(pf,16); pf += __shfl_xor(pf,32);
        pg += __shfl_xor(pg,16); pg += __shfl_xor(pg,32);
        if (g==0){
          tmpF[((lt*16+col)*OUT_+o2)*4 + w] = pf;
          tmpG[((lt*16+col)*OUT_+o2)*4 + w] = pg;
        }
      }
    }
  }
  __syncthreads();
  for (int idx=tid; idx<800; idx+=256){
    float4 f4 = *(const float4*)(tmpF + idx*4);
    float4 g4 = *(const float4*)(tmpG + idx*4);
    int o2 = idx % 5, rest = idx / 5;
    int b  = rest % 16, lt = rest / 16;
    fxeS[b*50 + lt*5 + o2] = f4.x+f4.y+f4.z+f4.w;
    gxeS[b*50 + lt*5 + o2] = g4.x+g4.y+g4.z+g4.w;
  }

  // decoder hoists
  f16x8 aW1[4];
  #pragma unroll
  for (int kf=0;kf<4;++kf){
    U4 cv;
    #pragma unroll
    for (int i=0;i<4;++i){
      int ep = (kf&1)*16 + g*4 + i;
      cv.u[i] = wsu[WS_W1HCP + (ep*64 + lw)*2 + (kf>>1)];
    }
    aW1[kf] = cv.v;
  }
  f16x8 aGh[4][2];
  #pragma unroll
  for (int q=0;q<4;++q)
    #pragma unroll
    for (int kf=0;kf<2;++kf){
      U4 cv;
      #pragma unroll
      for (int i=0;i<4;++i)
        cv.u[i] = wsu[WS_DECPK + ((kf*16 + g*4 + i)*64 + lw)*4 + q];
      aGh[q][kf] = cv.v;
    }
  f16x8 aG0[4];
  #pragma unroll
  for (int q=0;q<4;++q){
    U4 cv;
    #pragma unroll
    for (int i=0;i<4;++i)
      cv.u[i] = (g==0) ? wsu[WS_DECY2 + (i*64 + lw)*4 + q] : 0u;
    aG0[q] = cv.v;
  }
  float4 bD[4];
  #pragma unroll
  for (int r=0;r<4;++r) bD[r] = *(const float4*)(ws + WS_DECB + (u0+r)*4);
  float4 b1v = *(const float4*)(dec_attn_b1 + u0);
  float4 w2v = *(const float4*)(dec_attn_w2 + u0);
  float fcbv[OUT_], fw2v[OUT_][OUT_];
  #pragma unroll
  for (int o2=0;o2<OUT_;++o2){
    fcbv[o2] = fc_b[o2];
    #pragma unroll
    for (int j=0;j<OUT_;++j) fw2v[o2][j] = fc_w[o2*69 + 64 + j];
  }

  // decoder init
  h[0]=hd4.x; h[1]=hd4.y; h[2]=hd4.z; h[3]=hd4.w;
  c[0]=cd4.x; c[1]=cd4.y; c[2]=cd4.z; c[3]=cd4.w;
  *(uint2*)&hxD[0][col][u0>>1] = make_uint2(pack_rtz(h[0],h[1]), pack_rtz(h[2],h[3]));
  *(uint2*)&cxD[0][col][u0>>1] = make_uint2(pack_rtz(c[0],c[1]), pack_rtz(c[2],c[3]));
  __syncthreads();

  float at[L_];
  float inv = 0.f;
  p = 0;
  for (int t=0; t<L_; ++t){
    f16x8 hB[2], cB[2];
    { U4 t0; t0.q = *(const uint4*)&hxD[p][col][g*4];      hB[0]=t0.v; }
    { U4 t1; t1.q = *(const uint4*)&hxD[p][col][16 + g*4]; hB[1]=t1.v; }
    { U4 t2; t2.q = *(const uint4*)&cxD[p][col][g*4];      cB[0]=t2.v; }
    { U4 t3; t3.q = *(const uint4*)&cxD[p][col][16 + g*4]; cB[1]=t3.v; }

    f32x4 vb = { b1v.x, b1v.y, b1v.z, b1v.w };
    vb = __builtin_amdgcn_mfma_f32_16x16x32_f16(aW1[0], hB[0], vb, 0,0,0);
    vb = __builtin_amdgcn_mfma_f32_16x16x32_f16(aW1[1], hB[1], vb, 0,0,0);
    vb = __builtin_amdgcn_mfma_f32_16x16x32_f16(aW1[2], cB[0], vb, 0,0,0);
    vb = __builtin_amdgcn_mfma_f32_16x16x32_f16(aW1[3], cB[1], vb, 0,0,0);

    #pragma unroll
    for (int lt=0;lt<L_;++lt){
      float zp = tanhf_(preC[lt][0] + vb[0]) * w2v.x
               + tanhf_(preC[lt][1] + vb[1]) * w2v.y
               + tanhf_(preC[lt][2] + vb[2]) * w2v.z
               + tanhf_(preC[lt][3] + vb[3]) * w2v.w;
      zp += __shfl_xor(zp,16);
      zp += __shfl_xor(zp,32);
      at[lt] = zp;
    }
    if (g==0){
      #pragma unroll
      for (int lt=0;lt<L_;++lt) sred[(lt*16+col)*4 + w] = at[lt];
    }
    __syncthreads();
    #pragma unroll
    for (int lt=0;lt<L_;++lt){
      float4 s4 = *(const float4*)(sred + (lt*16+col)*4);
      at[lt] = s4.x + s4.y + s4.z + s4.w;
    }
    float mx = at[0];
    #pragma unroll
    for (int lt=1;lt<L_;++lt) mx = fmaxf(mx, at[lt]);
    float ssum = 0.f;
    #pragma unroll
    for (int lt=0;lt<L_;++lt){ at[lt] = __expf(at[lt]-mx); ssum += at[lt]; }
    inv = 1.f/ssum;

    U4 ycv; ycv.u[0]=0u; ycv.u[1]=0u; ycv.u[2]=0u; ycv.u[3]=0u;
    if (g==0){
      const float* fx = fxeS + col*50;
      const float* yb = ybS + col*50 + t*5;
      float yt[OUT_];
      #pragma unroll
      for (int o2=0;o2<OUT_;++o2){
        float sv = 0.f;
        #pragma unroll
        for (int lt=0;lt<L_;++lt) sv += at[lt]*fx[lt*5+o2];
        float v = sv*inv + fcbv[o2];
        #pragma unroll
        for (int j=0;j<OUT_;++j) v += yb[j]*fw2v[o2][j];
        yt[o2] = v;
      }
      ycv.u[0] = pack_rtn(yt[0], yt[1]);
      ycv.u[1] = pack_rtn(yt[2], yt[3]);
      ycv.u[2] = pack_rtn(yt[4], 0.f);
    }
    f32x4 accQ[4];
    #pragma unroll
    for (int q=0;q<4;++q){
      accQ[q][0]=((const float*)&bD[0])[q];
      accQ[q][1]=((const float*)&bD[1])[q];
      accQ[q][2]=((const float*)&bD[2])[q];
      accQ[q][3]=((const float*)&bD[3])[q];
    }
    #pragma unroll
    for (int q=0;q<4;++q){
      accQ[q] = __builtin_amdgcn_mfma_f32_16x16x32_f16(aG0[q], ycv.v, accQ[q], 0,0,0);
      accQ[q] = __builtin_amdgcn_mfma_f32_16x16x32_f16(aGh[q][0], hB[0], accQ[q], 0,0,0);
      accQ[q] = __builtin_amdgcn_mfma_f32_16x16x32_f16(aGh[q][1], hB[1], accQ[q], 0,0,0);
    }
    #pragma unroll
    for (int r=0;r<4;++r){
      float ig=sigmf(accQ[0][r]), fg=sigmf(accQ[1][r]), gg=tanhf_(accQ[2][r]), og=sigmf(accQ[3][r]);
      c[r]=fg*c[r]+ig*gg;
      h[r]=og*tanhf_(c[r]);
    }
    *(uint2*)&hxD[p^1][col][u0>>1] = make_uint2(pack_rtz(h[0],h[1]), pack_rtz(h[2],h[3]));
    *(uint2*)&cxD[p^1][col][u0>>1] = make_uint2(pack_rtz(c[0],c[1]), pack_rtz(c[2],c[3]));
    __syncthreads();
    p ^= 1;
  }

  // epilogue
  {
    float fcA[OUT_][4];
    #pragma unroll
    for (int o2=0;o2<OUT_;++o2)
      #pragma unroll
      for (int r=0;r<4;++r) fcA[o2][r] = fcout_w[o2*128 + u0 + r];
    #pragma unroll
    for (int o2=0;o2<OUT_;++o2){
      float pv = fcA[o2][0]*h[0] + fcA[o2][1]*h[1] + fcA[o2][2]*h[2] + fcA[o2][3]*h[3];
      pv += __shfl_xor(pv,16);
      pv += __shfl_xor(pv,32);
      if (g==0) sred[(o2*16+col)*4 + w] = pv;
    }
  }
  __syncthreads();
  if (w==0 && g==0){
    const float* gx = gxeS + col*50;
    #pragma unroll
    for (int o2=0;o2<OUT_;++o2){
      float4 s4 = *(const float4*)(sred + (o2*16+col)*4);
      float sv = 0.f;
      #pragma unroll
      for (int lt=0;lt<L_;++lt) sv += at[lt]*gx[lt*5+o2];
      out[(size_t)(b0+col)*OUT_ + o2] = s4.x+s4.y+s4.z+s4.w + sv*inv + fcout_b[o2];
    }
  }
}

extern "C" void kernel_launch(void* const* d_in, const int* in_sizes, int n_in,
                              void* d_out, int out_size, void* d_ws, size_t ws_size,
                              hipStream_t stream) {
  const float* x          = (const float*)d_in[0];
  const float* y_hist     = (const float*)d_in[1];
  const float* h0_enc     = (const float*)d_in[2];
  const float* c0_enc     = (const float*)d_in[3];
  const float* h0_dec     = (const float*)d_in[4];
  const float* c0_dec     = (const float*)d_in[5];
  const float* enc_attn_w = (const float*)d_in[6];
  const float* enc_Wih    = (const float*)d_in[8];
  const float* enc_Whh    = (const float*)d_in[9];
  const float* enc_bih    = (const float*)d_in[10];
  const float* enc_bhh    = (const float*)d_in[11];
  const float* dec_attn_w1= (const float*)d_in[12];
  const float* dec_attn_b1= (const float*)d_in[13];
  const float* dec_attn_w2= (const float*)d_in[14];
  const float* dec_Wih    = (const float*)d_in[16];
  const float* dec_Whh    = (const float*)d_in[17];
  const float* dec_bih    = (const float*)d_in[18];
  const float* dec_bhh    = (const float*)d_in[19];
  const float* fc_w       = (const float*)d_in[20];
  const float* fc_b       = (const float*)d_in[21];
  const float* fcout_w    = (const float*)d_in[22];
  const float* fcout_b    = (const float*)d_in[23];
  float* ws = (float*)d_ws;
  float* out = (float*)d_out;

  hipLaunchKernelGGL(prep_kernel, dim3(128), dim3(256), 0, stream,
                     enc_Wih, enc_Whh, enc_bih, enc_bhh,
                     dec_Wih, dec_Whh, dec_bih, dec_bhh,
                     dec_attn_w1, ws);
  hipLaunchKernelGGL(darnn_fused, dim3(B_/16), dim3(256), 0, stream,
                     x, enc_attn_w, y_hist,
                     h0_enc, c0_enc, h0_dec, c0_dec,
                     dec_attn_b1, dec_attn_w2,
                     fc_w, fc_b, fcout_w, fcout_b, ws, out);
}

// Round 6
// 214.826 us; speedup vs baseline: 1.3209x; 1.0270x over previous
//
#include <hip/hip_runtime.h>

// Problem constants
#define B_  8192
#define L_  10
#define D_  128
#define H_  64
#define OUT_ 5

typedef _Float16 h2 __attribute__((ext_vector_type(2)));
typedef _Float16 f16x8 __attribute__((ext_vector_type(8)));
typedef float f32x4 __attribute__((ext_vector_type(4)));
typedef unsigned int uint;

// ws dword layout:
#define WS_ENCPK   0        // [kp<96][l]: uint4, dword q = half2(W[q*64+l][2kp], [2kp+1]); k<128: Wih, else Whh
#define WS_ENCB    24576    // 256 floats: [u][q] = bih+bhh
#define WS_DECY2   24832    // [i<4][l<64]: uint4, comp q = half2(decWih[q*64+l][2i], [2i+1]) zero-padded k>=5
#define WS_DECPK   26112    // [ep<32][l]: uint4, half2(decWhh[q*64+l][2ep], [2ep+1])
#define WS_DECB    34304    // 256 floats: [u][q]
#define WS_W1HCP   34560    // [ep<32][l]: uint2 {half2 W1h pair, half2 W1c pair}
#define WS_W1XP    38656    // [ep<32][l]: uint half2 W1x pair

__device__ __forceinline__ float sigmf(float x){ return 1.f/(1.f+__expf(-x)); }
__device__ __forceinline__ float tanhf_(float x){ return 1.f - 2.f/(1.f+__expf(2.f*x)); }
__device__ __forceinline__ uint pack_rtz(float a, float b){
  return __builtin_bit_cast(uint, __builtin_amdgcn_cvt_pkrtz(a, b));
}
__device__ __forceinline__ uint pack_rtn(float a, float b){
  h2 v; v.x = (_Float16)a; v.y = (_Float16)b;
  return __builtin_bit_cast(uint, v);
}

union U4 { uint u[4]; uint4 q; f16x8 v; };

__global__ void prep_kernel(const float* __restrict__ encWih, const float* __restrict__ encWhh,
                            const float* __restrict__ encbih, const float* __restrict__ encbhh,
                            const float* __restrict__ decWih, const float* __restrict__ decWhh,
                            const float* __restrict__ decbih, const float* __restrict__ decbhh,
                            const float* __restrict__ w1, float* __restrict__ wsf)
{
  uint* ws = (uint*)wsf;
  int stride = gridDim.x * blockDim.x;
  int tid0 = blockIdx.x * blockDim.x + threadIdx.x;

  for (int idx = tid0; idx < 96*64; idx += stride) {
    int kp = idx >> 6, l = idx & 63;
    uint4 o; uint* op = (uint*)&o;
    #pragma unroll
    for (int q=0;q<4;++q){
      int j = q*64 + l;
      int k0 = 2*kp, k1 = 2*kp+1;
      float a = (k0 < 128) ? encWih[j*128 + k0] : encWhh[j*64 + (k0-128)];
      float b = (k1 < 128) ? encWih[j*128 + k1] : encWhh[j*64 + (k1-128)];
      op[q] = pack_rtn(a,b);
    }
    ((uint4*)(ws + WS_ENCPK))[idx] = o;
  }
  for (int idx = tid0; idx < 256; idx += stride) {
    int l = idx >> 2, q = idx & 3, j = q*64+l;
    wsf[WS_ENCB+idx] = encbih[j] + encbhh[j];
  }
  for (int idx = tid0; idx < 4*64; idx += stride) {
    int i = idx >> 6, l = idx & 63;
    uint4 o; uint* op = (uint*)&o;
    #pragma unroll
    for (int q=0;q<4;++q){
      int j = q*64 + l;
      int k0 = 2*i, k1 = 2*i+1;
      float a = (k0 < 5) ? decWih[j*5 + k0] : 0.f;
      float b = (k1 < 5) ? decWih[j*5 + k1] : 0.f;
      op[q] = pack_rtn(a,b);
    }
    ((uint4*)(ws + WS_DECY2))[idx] = o;
  }
  for (int idx = tid0; idx < 32*64; idx += stride) {
    int ep = idx >> 6, l = idx & 63;
    uint4 o; uint* op = (uint*)&o;
    #pragma unroll
    for (int q=0;q<4;++q){
      int j = q*64 + l;
      op[q] = pack_rtn(decWhh[j*64 + 2*ep], decWhh[j*64 + 2*ep+1]);
    }
    ((uint4*)(ws + WS_DECPK))[idx] = o;
  }
  for (int idx = tid0; idx < 256; idx += stride) {
    int l = idx >> 2, q = idx & 3, j = q*64+l;
    wsf[WS_DECB+idx] = decbih[j] + decbhh[j];
  }
  for (int idx = tid0; idx < 32*64; idx += stride) {
    int ep = idx >> 6, l = idx & 63;
    uint2 o;
    o.x = pack_rtn(w1[l*192 + 2*ep],      w1[l*192 + 2*ep+1]);
    o.y = pack_rtn(w1[l*192 + 64 + 2*ep], w1[l*192 + 64 + 2*ep+1]);
    ((uint2*)(ws + WS_W1HCP))[idx] = o;
  }
  for (int idx = tid0; idx < 32*64; idx += stride) {
    int ep = idx >> 6, l = idx & 63;
    ws[WS_W1XP + idx] = pack_rtn(w1[l*192 + 128 + 2*ep], w1[l*192 + 128 + 2*ep+1]);
  }
}

// LDS arena (bytes), total 52608 (static, 2 blocks/CU):
//   enc phase : wiS [5][16][136] f16 = 21760 @0 (5-row double-use: t0-4, then t5-9)
//               HXE @21760 (4608) | XES @26368 (23040) | YBS @49408 (3200)
//   post-enc  : tmpF @0 (12800) | tmpG @12800 (12800)   (over dead wiS/HXE)
//               HXD @25600 | CXD @30208 | SRED @34816 | FXE @37376 | GXE @40576
//               (all over dead HXE/XES; YBS never aliased)
#define SM_WIS   0
#define SM_HXE   21760
#define SM_XES   26368
#define SM_YBS   49408
#define SM_TMPF  0
#define SM_TMPG  12800
#define SM_HXD   25600
#define SM_CXD   30208
#define SM_SRED  34816
#define SM_FXE   37376
#define SM_GXE   40576
#define SM_TOTAL 52608

// Fused kernel, JIT-G variant: no gq register array (R5 spilled ~37dw/lane).
// wiS stays live through the encoder; each enc step does 4 ds_read_b128 +
// 16 wi-MFMA + 8 h-MFMA, f32 accumulation end-to-end (one f16 round removed).
__global__ __launch_bounds__(256, 2) void darnn_fused(
    const float* __restrict__ x, const float* __restrict__ enc_attn_w,
    const float* __restrict__ y_hist,
    const float* __restrict__ h0e, const float* __restrict__ c0e,
    const float* __restrict__ h0d, const float* __restrict__ c0d,
    const float* __restrict__ dec_attn_b1, const float* __restrict__ dec_attn_w2,
    const float* __restrict__ fc_w, const float* __restrict__ fc_b,
    const float* __restrict__ fcout_w, const float* __restrict__ fcout_b,
    const float* __restrict__ ws,
    float* __restrict__ out)
{
  const int tid = threadIdx.x;
  const int l   = tid & 63;
  const int w   = tid >> 6;
  const int col = l & 15;          // batch sub-row (MFMA col)
  const int g   = l >> 4;          // k-group / C-row group
  const int b0  = blockIdx.x * 16;
  const int lw  = 16*w + col;      // row into 64-wide weight tables
  const int u0  = 16*w + 4*g;      // first hidden-unit of this lane's slice

  const uint* wsu = (const uint*)ws;

  __shared__ __align__(16) char smem_[SM_TOTAL];
  _Float16 (*wiS)[16][136] = reinterpret_cast<_Float16(*)[16][136]>(smem_ + SM_WIS);
  uint     (*hxE)[16][36] = reinterpret_cast<uint(*)[16][36]>(smem_ + SM_HXE);
  _Float16 (*xeS)[16][72] = reinterpret_cast<_Float16(*)[16][72]>(smem_ + SM_XES);
  float* tmpF = (float*)(smem_ + SM_TMPF);
  float* tmpG = (float*)(smem_ + SM_TMPG);
  uint     (*hxD)[16][36] = reinterpret_cast<uint(*)[16][36]>(smem_ + SM_HXD);
  uint     (*cxD)[16][36] = reinterpret_cast<uint(*)[16][36]>(smem_ + SM_CXD);
  float* sred = (float*)(smem_ + SM_SRED);
  float* fxeS = (float*)(smem_ + SM_FXE);
  float* gxeS = (float*)(smem_ + SM_GXE);
  float* ybS  = (float*)(smem_ + SM_YBS);

  // ---- early loads whose latency hides under the G score pass ----
  if (tid < 200){
    float4 yreg = *(const float4*)(y_hist + (size_t)b0*50 + tid*4);
    *(float4*)(ybS + tid*4) = yreg;
  }
  float4 hd4 = *(const float4*)(h0d + (size_t)(b0+col)*64 + u0);
  float4 cd4 = *(const float4*)(c0d + (size_t)(b0+col)*64 + u0);
  float4 he4 = *(const float4*)(h0e + (size_t)(b0+col)*64 + u0);
  float4 ce4 = *(const float4*)(c0e + (size_t)(b0+col)*64 + u0);

  // ---- weight fragments (gate-quadrant mapping; all enc fragments hoisted) ----
  f16x8 afr[4][4];   // enc Wih, tile im = gate
  #pragma unroll
  for (int im=0; im<4; ++im){
    #pragma unroll
    for (int kf=0; kf<4; ++kf){
      U4 cv;
      #pragma unroll
      for (int i=0;i<4;++i){
        int kp = kf*16 + g*4 + i;
        cv.u[i] = wsu[WS_ENCPK + (kp*64 + lw)*4 + im];
      }
      afr[im][kf] = cv.v;
    }
  }
  f16x8 aE[4][2];    // enc Whh, tile q = gate
  #pragma unroll
  for (int q=0;q<4;++q)
    #pragma unroll
    for (int kf=0;kf<2;++kf){
      U4 cv;
      #pragma unroll
      for (int i=0;i<4;++i)
        cv.u[i] = wsu[WS_ENCPK + ((64 + kf*16 + g*4 + i)*64 + lw)*4 + q];
      aE[q][kf] = cv.v;
    }
  float bias[4][4];
  #pragma unroll
  for (int im=0; im<4; ++im)
    #pragma unroll
    for (int r=0; r<4; ++r)
      bias[im][r] = ws[WS_ENCB + (u0 + r)*4 + im];

  // ---- phase A: coalesced score pass (thread = (bb, kc)) ----
  const int bb = tid >> 4;
  const int kc = tid & 15;
  const float* xb = x + (size_t)(b0+bb)*(L_*D_) + kc*8;

  float wxv[L_];
  #pragma unroll
  for (int t=0;t<L_;++t) wxv[t] = enc_attn_w[2*H_ + t];

  float s[8];
  #pragma unroll
  for (int j=0;j<8;++j) s[j]=0.f;
  #pragma unroll
  for (int t=0;t<L_;++t){
    float wx = wxv[t];
    float4 x0 = *(const float4*)(xb + t*D_);
    float4 x1 = *(const float4*)(xb + t*D_ + 4);
    s[0]+=x0.x*wx; s[1]+=x0.y*wx; s[2]+=x0.z*wx; s[3]+=x0.w*wx;
    s[4]+=x1.x*wx; s[5]+=x1.y*wx; s[6]+=x1.z*wx; s[7]+=x1.w*wx;
  }
  float m = s[0];
  #pragma unroll
  for (int j=1;j<8;++j) m = fmaxf(m, s[j]);
  m = fmaxf(m, __shfl_xor(m,1));
  m = fmaxf(m, __shfl_xor(m,2));
  m = fmaxf(m, __shfl_xor(m,4));
  m = fmaxf(m, __shfl_xor(m,8));
  float atw[8];
  float ss = 0.f;
  #pragma unroll
  for (int j=0;j<8;++j){ atw[j] = __expf(s[j]-m); ss += atw[j]; }
  ss += __shfl_xor(ss,1);
  ss += __shfl_xor(ss,2);
  ss += __shfl_xor(ss,4);
  ss += __shfl_xor(ss,8);
  float ainv = 1.f/ss;
  #pragma unroll
  for (int j=0;j<8;++j) atw[j] *= ainv;

  // ---- phase B1: wi rows t=0..4 -> wiS ----
  #pragma unroll
  for (int t=0;t<5;++t){
    float4 x0 = *(const float4*)(xb + t*D_);
    float4 x1 = *(const float4*)(xb + t*D_ + 4);
    uint4 o;
    o.x = pack_rtz(atw[0]*x0.x, atw[1]*x0.y);
    o.y = pack_rtz(atw[2]*x0.z, atw[3]*x0.w);
    o.z = pack_rtz(atw[4]*x1.x, atw[5]*x1.y);
    o.w = pack_rtz(atw[6]*x1.z, atw[7]*x1.w);
    *(uint4*)&wiS[t][bb][kc*8] = o;
  }

  // ---- encoder init ----
  float h[4], c[4], xer[L_][4];
  h[0]=he4.x; h[1]=he4.y; h[2]=he4.z; h[3]=he4.w;
  c[0]=ce4.x; c[1]=ce4.y; c[2]=ce4.z; c[3]=ce4.w;
  *(uint2*)&hxE[0][col][u0>>1] = make_uint2(pack_rtz(h[0],h[1]), pack_rtz(h[2],h[3]));
  __syncthreads();   // wiS rows 0-4 + hxE[0] visible

  int p = 0;
  // ---- encoder steps (JIT gates from wiS), halves split by wiS re-stage ----
  #pragma unroll
  for (int half=0; half<2; ++half){
    #pragma unroll
    for (int tt=0; tt<5; ++tt){
      const int t = half*5 + tt;
      U4 bu[4];
      #pragma unroll
      for (int kf=0;kf<4;++kf)
        bu[kf].q = *(const uint4*)&wiS[tt][col][kf*32 + g*8];
      f16x8 hB[2];
      { U4 t0; t0.q = *(const uint4*)&hxE[p][col][g*4];      hB[0]=t0.v; }
      { U4 t1; t1.q = *(const uint4*)&hxE[p][col][16 + g*4]; hB[1]=t1.v; }

      f32x4 acc[4];
      #pragma unroll
      for (int q=0;q<4;++q){
        acc[q][0]=bias[q][0]; acc[q][1]=bias[q][1];
        acc[q][2]=bias[q][2]; acc[q][3]=bias[q][3];
      }
      #pragma unroll
      for (int q=0;q<4;++q){
        #pragma unroll
        for (int kf=0;kf<4;++kf)
          acc[q] = __builtin_amdgcn_mfma_f32_16x16x32_f16(afr[q][kf], bu[kf].v, acc[q], 0,0,0);
        acc[q] = __builtin_amdgcn_mfma_f32_16x16x32_f16(aE[q][0], hB[0], acc[q], 0,0,0);
        acc[q] = __builtin_amdgcn_mfma_f32_16x16x32_f16(aE[q][1], hB[1], acc[q], 0,0,0);
      }
      #pragma unroll
      for (int r=0;r<4;++r){
        float ig=sigmf(acc[0][r]), fg=sigmf(acc[1][r]), gg=tanhf_(acc[2][r]), og=sigmf(acc[3][r]);
        c[r]=fg*c[r]+ig*gg;
        h[r]=og*tanhf_(c[r]);
        xer[t][r]=h[r];
      }
      uint2 hpk = make_uint2(pack_rtz(h[0],h[1]), pack_rtz(h[2],h[3]));
      *(uint2*)&xeS[t][col][u0] = hpk;
      *(uint2*)&hxE[p^1][col][u0>>1] = hpk;
      __syncthreads();
      p ^= 1;
    }
    if (half==0){
      // re-stage wiS with t=5..9 (x re-read, L2-warm-ish)
      #pragma unroll
      for (int t=5;t<L_;++t){
        float4 x0 = *(const float4*)(xb + t*D_);
        float4 x1 = *(const float4*)(xb + t*D_ + 4);
        uint4 o;
        o.x = pack_rtz(atw[0]*x0.x, atw[1]*x0.y);
        o.y = pack_rtz(atw[2]*x0.z, atw[3]*x0.w);
        o.z = pack_rtz(atw[4]*x1.x, atw[5]*x1.y);
        o.w = pack_rtz(atw[6]*x1.z, atw[7]*x1.w);
        *(uint4*)&wiS[t-5][bb][kc*8] = o;
      }
      __syncthreads();
    }
  }

  // ---- pre = xe @ W1x^T ----
  f16x8 aX[2];
  #pragma unroll
  for (int kf=0;kf<2;++kf){
    U4 cv;
    #pragma unroll
    for (int i=0;i<4;++i) cv.u[i] = wsu[WS_W1XP + (kf*16 + g*4 + i)*64 + lw];
    aX[kf] = cv.v;
  }
  f32x4 preC[L_];
  #pragma unroll
  for (int lt=0;lt<L_;++lt){
    f32x4 a = {0.f,0.f,0.f,0.f};
    U4 bu0, bu1;
    bu0.q = *(const uint4*)&xeS[lt][col][g*8];
    bu1.q = *(const uint4*)&xeS[lt][col][32 + g*8];
    a = __builtin_amdgcn_mfma_f32_16x16x32_f16(aX[0], bu0.v, a, 0,0,0);
    a = __builtin_amdgcn_mfma_f32_16x16x32_f16(aX[1], bu1.v, a, 0,0,0);
    preC[lt] = a;
  }

  // ---- fxe/gxe precompute (f32-exact from xer) ----
  {
    float fw1v[OUT_][4], gw1v[OUT_][4];
    #pragma unroll
    for (int o2=0;o2<OUT_;++o2)
      #pragma unroll
      for (int r=0;r<4;++r){
        fw1v[o2][r] = fc_w[o2*69 + u0 + r];
        gw1v[o2][r] = fcout_w[o2*128 + 64 + u0 + r];
      }
    #pragma unroll
    for (int lt=0;lt<L_;++lt){
      #pragma unroll
      for (int o2=0;o2<OUT_;++o2){
        float pf = fw1v[o2][0]*xer[lt][0] + fw1v[o2][1]*xer[lt][1]
                 + fw1v[o2][2]*xer[lt][2] + fw1v[o2][3]*xer[lt][3];
        float pg = gw1v[o2][0]*xer[lt][0] + gw1v[o2][1]*xer[lt][1]
                 + gw1v[o2][2]*xer[lt][2] + gw1v[o2][3]*xer[lt][3];
        pf += __shfl_xor(pf,16); pf += __shfl_xor(pf,32);
        pg += __shfl_xor(pg,16); pg += __shfl_xor(pg,32);
        if (g==0){
          tmpF[((lt*16+col)*OUT_+o2)*4 + w] = pf;
          tmpG[((lt*16+col)*OUT_+o2)*4 + w] = pg;
        }
      }
    }
  }
  __syncthreads();
  for (int idx=tid; idx<800; idx+=256){
    float4 f4 = *(const float4*)(tmpF + idx*4);
    float4 g4 = *(const float4*)(tmpG + idx*4);
    int o2 = idx % 5, rest = idx / 5;
    int b  = rest % 16, lt = rest / 16;
    fxeS[b*50 + lt*5 + o2] = f4.x+f4.y+f4.z+f4.w;
    gxeS[b*50 + lt*5 + o2] = g4.x+g4.y+g4.z+g4.w;
  }

  // ---- decoder hoists ----
  f16x8 aW1[4];
  #pragma unroll
  for (int kf=0;kf<4;++kf){
    U4 cv;
    #pragma unroll
    for (int i=0;i<4;++i){
      int ep = (kf&1)*16 + g*4 + i;
      cv.u[i] = wsu[WS_W1HCP + (ep*64 + lw)*2 + (kf>>1)];
    }
    aW1[kf] = cv.v;
  }
  f16x8 aGh[4][2];
  #pragma unroll
  for (int q=0;q<4;++q)
    #pragma unroll
    for (int kf=0;kf<2;++kf){
      U4 cv;
      #pragma unroll
      for (int i=0;i<4;++i)
        cv.u[i] = wsu[WS_DECPK + ((kf*16 + g*4 + i)*64 + lw)*4 + q];
      aGh[q][kf] = cv.v;
    }
  f16x8 aG0[4];
  #pragma unroll
  for (int q=0;q<4;++q){
    U4 cv;
    #pragma unroll
    for (int i=0;i<4;++i)
      cv.u[i] = (g==0) ? wsu[WS_DECY2 + (i*64 + lw)*4 + q] : 0u;
    aG0[q] = cv.v;
  }
  float4 bD[4];
  #pragma unroll
  for (int r=0;r<4;++r) bD[r] = *(const float4*)(ws + WS_DECB + (u0+r)*4);
  float4 b1v = *(const float4*)(dec_attn_b1 + u0);
  float4 w2v = *(const float4*)(dec_attn_w2 + u0);
  float fcbv[OUT_], fw2v[OUT_][OUT_];
  #pragma unroll
  for (int o2=0;o2<OUT_;++o2){
    fcbv[o2] = fc_b[o2];
    #pragma unroll
    for (int j=0;j<OUT_;++j) fw2v[o2][j] = fc_w[o2*69 + 64 + j];
  }

  // ---- decoder init ----
  h[0]=hd4.x; h[1]=hd4.y; h[2]=hd4.z; h[3]=hd4.w;
  c[0]=cd4.x; c[1]=cd4.y; c[2]=cd4.z; c[3]=cd4.w;
  *(uint2*)&hxD[0][col][u0>>1] = make_uint2(pack_rtz(h[0],h[1]), pack_rtz(h[2],h[3]));
  *(uint2*)&cxD[0][col][u0>>1] = make_uint2(pack_rtz(c[0],c[1]), pack_rtz(c[2],c[3]));
  __syncthreads();

  float at[L_];
  float inv = 0.f;
  p = 0;
  for (int t=0; t<L_; ++t){
    f16x8 hB[2], cB[2];
    { U4 t0; t0.q = *(const uint4*)&hxD[p][col][g*4];      hB[0]=t0.v; }
    { U4 t1; t1.q = *(const uint4*)&hxD[p][col][16 + g*4]; hB[1]=t1.v; }
    { U4 t2; t2.q = *(const uint4*)&cxD[p][col][g*4];      cB[0]=t2.v; }
    { U4 t3; t3.q = *(const uint4*)&cxD[p][col][16 + g*4]; cB[1]=t3.v; }

    f32x4 vb = { b1v.x, b1v.y, b1v.z, b1v.w };
    vb = __builtin_amdgcn_mfma_f32_16x16x32_f16(aW1[0], hB[0], vb, 0,0,0);
    vb = __builtin_amdgcn_mfma_f32_16x16x32_f16(aW1[1], hB[1], vb, 0,0,0);
    vb = __builtin_amdgcn_mfma_f32_16x16x32_f16(aW1[2], cB[0], vb, 0,0,0);
    vb = __builtin_amdgcn_mfma_f32_16x16x32_f16(aW1[3], cB[1], vb, 0,0,0);

    #pragma unroll
    for (int lt=0;lt<L_;++lt){
      float zp = tanhf_(preC[lt][0] + vb[0]) * w2v.x
               + tanhf_(preC[lt][1] + vb[1]) * w2v.y
               + tanhf_(preC[lt][2] + vb[2]) * w2v.z
               + tanhf_(preC[lt][3] + vb[3]) * w2v.w;
      zp += __shfl_xor(zp,16);
      zp += __shfl_xor(zp,32);
      at[lt] = zp;
    }
    if (g==0){
      #pragma unroll
      for (int lt=0;lt<L_;++lt) sred[(lt*16+col)*4 + w] = at[lt];
    }
    __syncthreads();
    #pragma unroll
    for (int lt=0;lt<L_;++lt){
      float4 s4 = *(const float4*)(sred + (lt*16+col)*4);
      at[lt] = s4.x + s4.y + s4.z + s4.w;
    }
    float mx = at[0];
    #pragma unroll
    for (int lt=1;lt<L_;++lt) mx = fmaxf(mx, at[lt]);
    float ssum = 0.f;
    #pragma unroll
    for (int lt=0;lt<L_;++lt){ at[lt] = __expf(at[lt]-mx); ssum += at[lt]; }
    inv = 1.f/ssum;

    U4 ycv; ycv.u[0]=0u; ycv.u[1]=0u; ycv.u[2]=0u; ycv.u[3]=0u;
    if (g==0){
      const float* fx = fxeS + col*50;
      const float* yb = ybS + col*50 + t*5;
      float yt[OUT_];
      #pragma unroll
      for (int o2=0;o2<OUT_;++o2){
        float sv = 0.f;
        #pragma unroll
        for (int lt=0;lt<L_;++lt) sv += at[lt]*fx[lt*5+o2];
        float v = sv*inv + fcbv[o2];
        #pragma unroll
        for (int j=0;j<OUT_;++j) v += yb[j]*fw2v[o2][j];
        yt[o2] = v;
      }
      ycv.u[0] = pack_rtn(yt[0], yt[1]);
      ycv.u[1] = pack_rtn(yt[2], yt[3]);
      ycv.u[2] = pack_rtn(yt[4], 0.f);
    }
    f32x4 accQ[4];
    #pragma unroll
    for (int q=0;q<4;++q){
      accQ[q][0]=((const float*)&bD[0])[q];
      accQ[q][1]=((const float*)&bD[1])[q];
      accQ[q][2]=((const float*)&bD[2])[q];
      accQ[q][3]=((const float*)&bD[3])[q];
    }
    #pragma unroll
    for (int q=0;q<4;++q){
      accQ[q] = __builtin_amdgcn_mfma_f32_16x16x32_f16(aG0[q], ycv.v, accQ[q], 0,0,0);
      accQ[q] = __builtin_amdgcn_mfma_f32_16x16x32_f16(aGh[q][0], hB[0], accQ[q], 0,0,0);
      accQ[q] = __builtin_amdgcn_mfma_f32_16x16x32_f16(aGh[q][1], hB[1], accQ[q], 0,0,0);
    }
    #pragma unroll
    for (int r=0;r<4;++r){
      float ig=sigmf(accQ[0][r]), fg=sigmf(accQ[1][r]), gg=tanhf_(accQ[2][r]), og=sigmf(accQ[3][r]);
      c[r]=fg*c[r]+ig*gg;
      h[r]=og*tanhf_(c[r]);
    }
    *(uint2*)&hxD[p^1][col][u0>>1] = make_uint2(pack_rtz(h[0],h[1]), pack_rtz(h[2],h[3]));
    *(uint2*)&cxD[p^1][col][u0>>1] = make_uint2(pack_rtz(c[0],c[1]), pack_rtz(c[2],c[3]));
    __syncthreads();
    p ^= 1;
  }

  // ---- epilogue ----
  {
    float fcA[OUT_][4];
    #pragma unroll
    for (int o2=0;o2<OUT_;++o2)
      #pragma unroll
      for (int r=0;r<4;++r) fcA[o2][r] = fcout_w[o2*128 + u0 + r];
    #pragma unroll
    for (int o2=0;o2<OUT_;++o2){
      float pv = fcA[o2][0]*h[0] + fcA[o2][1]*h[1] + fcA[o2][2]*h[2] + fcA[o2][3]*h[3];
      pv += __shfl_xor(pv,16);
      pv += __shfl_xor(pv,32);
      if (g==0) sred[(o2*16+col)*4 + w] = pv;
    }
  }
  __syncthreads();
  if (w==0 && g==0){
    const float* gx = gxeS + col*50;
    #pragma unroll
    for (int o2=0;o2<OUT_;++o2){
      float4 s4 = *(const float4*)(sred + (o2*16+col)*4);
      float sv = 0.f;
      #pragma unroll
      for (int lt=0;lt<L_;++lt) sv += at[lt]*gx[lt*5+o2];
      out[(size_t)(b0+col)*OUT_ + o2] = s4.x+s4.y+s4.z+s4.w + sv*inv + fcout_b[o2];
    }
  }
}

extern "C" void kernel_launch(void* const* d_in, const int* in_sizes, int n_in,
                              void* d_out, int out_size, void* d_ws, size_t ws_size,
                              hipStream_t stream) {
  const float* x          = (const float*)d_in[0];
  const float* y_hist     = (const float*)d_in[1];
  const float* h0_enc     = (const float*)d_in[2];
  const float* c0_enc     = (const float*)d_in[3];
  const float* h0_dec     = (const float*)d_in[4];
  const float* c0_dec     = (const float*)d_in[5];
  const float* enc_attn_w = (const float*)d_in[6];
  const float* enc_Wih    = (const float*)d_in[8];
  const float* enc_Whh    = (const float*)d_in[9];
  const float* enc_bih    = (const float*)d_in[10];
  const float* enc_bhh    = (const float*)d_in[11];
  const float* dec_attn_w1= (const float*)d_in[12];
  const float* dec_attn_b1= (const float*)d_in[13];
  const float* dec_attn_w2= (const float*)d_in[14];
  const float* dec_Wih    = (const float*)d_in[16];
  const float* dec_Whh    = (const float*)d_in[17];
  const float* dec_bih    = (const float*)d_in[18];
  const float* dec_bhh    = (const float*)d_in[19];
  const float* fc_w       = (const float*)d_in[20];
  const float* fc_b       = (const float*)d_in[21];
  const float* fcout_w    = (const float*)d_in[22];
  const float* fcout_b    = (const float*)d_in[23];
  float* ws = (float*)d_ws;
  float* out = (float*)d_out;

  hipLaunchKernelGGL(prep_kernel, dim3(128), dim3(256), 0, stream,
                     enc_Wih, enc_Whh, enc_bih, enc_bhh,
                     dec_Wih, dec_Whh, dec_bih, dec_bhh,
                     dec_attn_w1, ws);
  hipLaunchKernelGGL(darnn_fused, dim3(B_/16), dim3(256), 0, stream,
                     x, enc_attn_w, y_hist,
                     h0_enc, c0_enc, h0_dec, c0_dec,
                     dec_attn_b1, dec_attn_w2,
                     fc_w, fc_b, fcout_w, fcout_b, ws, out);
}